// Round 10
// baseline (211.208 us; speedup 1.0000x reference)
//
#include <hip/hip_runtime.h>

#define NN 40000
#define NE 640000
#define NG 64
#define SCAN_NB ((NN + 255) / 256)   // 157 blocks

__device__ __forceinline__ float fcomp(const float4& v, int t) {
    return t == 0 ? v.x : t == 1 ? v.y : t == 2 ? v.z : v.w;
}

// ================= CSR build =================
__global__ void hist_kernel(const int* __restrict__ dst, int* __restrict__ deg) {
    int e = blockIdx.x * blockDim.x + threadIdx.x;
    if (e < NE) atomicAdd(&deg[dst[e]], 1);
}

__global__ __launch_bounds__(256) void scan1_kernel(const int* __restrict__ deg,
                                                    int* __restrict__ rowptr,
                                                    int* __restrict__ bsum) {
    __shared__ int ws[4];
    __shared__ int wpre[4];
    int i = blockIdx.x * 256 + threadIdx.x;
    int lane = threadIdx.x & 63, wid = threadIdx.x >> 6;
    int v = (i < NN) ? deg[i] : 0;
    int incl = v;
#pragma unroll
    for (int off = 1; off < 64; off <<= 1) {
        int u = __shfl_up(incl, off, 64);
        if (lane >= off) incl += u;
    }
    if (lane == 63) ws[wid] = incl;
    __syncthreads();
    if (threadIdx.x == 0) {
        int s = 0;
#pragma unroll
        for (int w = 0; w < 4; ++w) { wpre[w] = s; s += ws[w]; }
        bsum[blockIdx.x] = s;
    }
    __syncthreads();
    if (i < NN) rowptr[i] = wpre[wid] + (incl - v);
}

__global__ __launch_bounds__(256) void scan2_kernel(int* __restrict__ bsum,
                                                    int* __restrict__ rowptr) {
    __shared__ int ws[4];
    __shared__ int wpre[4];
    int t = threadIdx.x;
    int lane = t & 63, wid = t >> 6;
    int v = (t < SCAN_NB) ? bsum[t] : 0;
    int incl = v;
#pragma unroll
    for (int off = 1; off < 64; off <<= 1) {
        int u = __shfl_up(incl, off, 64);
        if (lane >= off) incl += u;
    }
    if (lane == 63) ws[wid] = incl;
    __syncthreads();
    if (t == 0) {
        int s = 0;
#pragma unroll
        for (int w = 0; w < 4; ++w) { wpre[w] = s; s += ws[w]; }
        rowptr[NN] = s;
    }
    __syncthreads();
    if (t < SCAN_NB) bsum[t] = wpre[wid] + (incl - v);
}

__global__ __launch_bounds__(256) void scan3_kernel(int* __restrict__ rowptr,
                                                    const int* __restrict__ bsum,
                                                    int* __restrict__ cursor) {
    int i = blockIdx.x * 256 + threadIdx.x;
    if (i < NN) {
        int e = rowptr[i] + bsum[blockIdx.x];
        rowptr[i] = e;
        cursor[i] = e;
    }
}

__global__ void fill_kernel(const int* __restrict__ src, const int* __restrict__ dst,
                            int* __restrict__ cursor, int* __restrict__ col) {
    int e = blockIdx.x * blockDim.x + threadIdx.x;
    if (e < NE) {
        int pos = atomicAdd(&cursor[dst[e]], 1);
        col[pos] = src[e];
    }
}

// ====== fused L1: gather x (D=32) into LDS, then conv1 32->128 ======
// grid = NN/32 = 1250 exactly
__global__ __launch_bounds__(256, 4) void fconv1_kernel(
        const float4* __restrict__ x,      // N x 8
        const int* __restrict__ rowptr,
        const int* __restrict__ col,
        const float4* __restrict__ Wrel,   // 32 x 32
        const float4* __restrict__ Wroot,  // 32 x 32
        const float4* __restrict__ bias,   // 32
        float4* __restrict__ out, int n) { // N x 32
    __shared__ float4 sA[32][9];           // agg tile (+pad)
    __shared__ float4 sR[32 * 32];         // 16 KB
    __shared__ float4 sT[32 * 32];         // 16 KB
    for (int i = threadIdx.x; i < 32 * 32; i += 256) { sR[i] = Wrel[i]; sT[i] = Wroot[i]; }
    int t = threadIdx.x;
    // ---- Phase A: 1 task/thread: (node, c) gather-sum of x ----
    {
        int na = t >> 3, cA = t & 7;
        int node = blockIdx.x * 32 + na;
        int beg = rowptr[node], end = rowptr[node + 1];
        float4 a = {0.f, 0.f, 0.f, 0.f};
        int e = beg;
        for (; e + 4 <= end; e += 4) {
            int c0 = col[e], c1 = col[e + 1], c2 = col[e + 2], c3 = col[e + 3];
            float4 v0 = x[(size_t)c0 * 8 + cA];
            float4 v1 = x[(size_t)c1 * 8 + cA];
            float4 v2 = x[(size_t)c2 * 8 + cA];
            float4 v3 = x[(size_t)c3 * 8 + cA];
            a.x += (v0.x + v1.x) + (v2.x + v3.x);
            a.y += (v0.y + v1.y) + (v2.y + v3.y);
            a.z += (v0.z + v1.z) + (v2.z + v3.z);
            a.w += (v0.w + v1.w) + (v2.w + v3.w);
        }
        for (; e < end; ++e) {
            float4 v = x[(size_t)col[e] * 8 + cA];
            a.x += v.x; a.y += v.y; a.z += v.z; a.w += v.w;
        }
        sA[na][cA] = a;
    }
    __syncthreads();
    // ---- Phase B: 2 nodes x 8 outputs per thread ----
    int jg = t % 16, mg = t / 16;
    int n0 = blockIdx.x * 32 + mg * 2;
    float4 bb0 = bias[2 * jg], bb1 = bias[2 * jg + 1];
    float4 acc00 = bb0, acc01 = bb1, acc10 = bb0, acc11 = bb1;
#pragma unroll 2
    for (int kc = 0; kc < 8; ++kc) {
        float4 a0 = sA[2 * mg][kc];
        float4 a1 = sA[2 * mg + 1][kc];
        float4 x0 = x[(size_t)n0 * 8 + kc];
        float4 x1 = x[(size_t)(n0 + 1) * 8 + kc];
#pragma unroll
        for (int tt = 0; tt < 4; ++tt) {
            int k = kc * 4 + tt;
            float4 wr0 = sR[k * 32 + 2 * jg], wr1 = sR[k * 32 + 2 * jg + 1];
            float4 wt0 = sT[k * 32 + 2 * jg], wt1 = sT[k * 32 + 2 * jg + 1];
            float av0 = fcomp(a0, tt), xv0 = fcomp(x0, tt);
            float av1 = fcomp(a1, tt), xv1 = fcomp(x1, tt);
            acc00.x += av0 * wr0.x + xv0 * wt0.x;
            acc00.y += av0 * wr0.y + xv0 * wt0.y;
            acc00.z += av0 * wr0.z + xv0 * wt0.z;
            acc00.w += av0 * wr0.w + xv0 * wt0.w;
            acc01.x += av0 * wr1.x + xv0 * wt1.x;
            acc01.y += av0 * wr1.y + xv0 * wt1.y;
            acc01.z += av0 * wr1.z + xv0 * wt1.z;
            acc01.w += av0 * wr1.w + xv0 * wt1.w;
            acc10.x += av1 * wr0.x + xv1 * wt0.x;
            acc10.y += av1 * wr0.y + xv1 * wt0.y;
            acc10.z += av1 * wr0.z + xv1 * wt0.z;
            acc10.w += av1 * wr0.w + xv1 * wt0.w;
            acc11.x += av1 * wr1.x + xv1 * wt1.x;
            acc11.y += av1 * wr1.y + xv1 * wt1.y;
            acc11.z += av1 * wr1.z + xv1 * wt1.z;
            acc11.w += av1 * wr1.w + xv1 * wt1.w;
        }
    }
    float4 r;
    r.x = fmaxf(acc00.x, 0.f); r.y = fmaxf(acc00.y, 0.f);
    r.z = fmaxf(acc00.z, 0.f); r.w = fmaxf(acc00.w, 0.f);
    out[(size_t)n0 * 32 + 2 * jg] = r;
    r.x = fmaxf(acc01.x, 0.f); r.y = fmaxf(acc01.y, 0.f);
    r.z = fmaxf(acc01.z, 0.f); r.w = fmaxf(acc01.w, 0.f);
    out[(size_t)n0 * 32 + 2 * jg + 1] = r;
    r.x = fmaxf(acc10.x, 0.f); r.y = fmaxf(acc10.y, 0.f);
    r.z = fmaxf(acc10.z, 0.f); r.w = fmaxf(acc10.w, 0.f);
    out[(size_t)(n0 + 1) * 32 + 2 * jg] = r;
    r.x = fmaxf(acc11.x, 0.f); r.y = fmaxf(acc11.y, 0.f);
    r.z = fmaxf(acc11.z, 0.f); r.w = fmaxf(acc11.w, 0.f);
    out[(size_t)(n0 + 1) * 32 + 2 * jg + 1] = r;
}

// ====== fused transform: y = h@Wrel, z = h@Wroot + b (layer 2, 128->64) ======
template<int K, int DOUT, int NPT>
__global__ __launch_bounds__(256, 6) void mmyz_kernel(
        const float4* __restrict__ h,
        const float4* __restrict__ Wrel,
        const float4* __restrict__ Wroot,
        const float4* __restrict__ bias,
        float4* __restrict__ y,
        float4* __restrict__ z, int n) {
    constexpr int JL = DOUT / 4, MG = 256 / JL, NPB = MG * NPT;
    constexpr int SLAB = (K * JL * 2 * 16 <= 16384) ? K : 32;
    constexpr int NS = K / SLAB;
    __shared__ float4 sR[SLAB * JL];
    __shared__ float4 sT[SLAB * JL];
    int jl = threadIdx.x % JL;
    int mg = threadIdx.x / JL;
    int node0 = blockIdx.x * NPB + mg * NPT;
    int nm[NPT]; bool ok[NPT];
#pragma unroll
    for (int m = 0; m < NPT; ++m) {
        int nd = node0 + m; ok[m] = nd < n; nm[m] = ok[m] ? nd : 0;
    }
    float4 bb = bias[jl];
    float4 ay[NPT], az[NPT];
#pragma unroll
    for (int m = 0; m < NPT; ++m) {
        ay[m].x = 0.f; ay[m].y = 0.f; ay[m].z = 0.f; ay[m].w = 0.f;
        az[m] = bb;
    }
    for (int s = 0; s < NS; ++s) {
        if (NS > 1) __syncthreads();
        for (int i = threadIdx.x; i < SLAB * JL; i += 256) {
            sR[i] = Wrel[s * SLAB * JL + i];
            sT[i] = Wroot[s * SLAB * JL + i];
        }
        __syncthreads();
#pragma unroll 2
        for (int kc = 0; kc < SLAB / 4; ++kc) {
            float4 h4[NPT];
#pragma unroll
            for (int m = 0; m < NPT; ++m)
                h4[m] = h[(size_t)nm[m] * (K / 4) + s * (SLAB / 4) + kc];
#pragma unroll
            for (int tt = 0; tt < 4; ++tt) {
                float4 wr = sR[(kc * 4 + tt) * JL + jl];
                float4 wt = sT[(kc * 4 + tt) * JL + jl];
#pragma unroll
                for (int m = 0; m < NPT; ++m) {
                    float hv = fcomp(h4[m], tt);
                    ay[m].x += hv * wr.x; ay[m].y += hv * wr.y;
                    ay[m].z += hv * wr.z; ay[m].w += hv * wr.w;
                    az[m].x += hv * wt.x; az[m].y += hv * wt.y;
                    az[m].z += hv * wt.z; az[m].w += hv * wt.w;
                }
            }
        }
    }
#pragma unroll
    for (int m = 0; m < NPT; ++m) {
        if (!ok[m]) continue;
        y[(size_t)nm[m] * JL + jl] = ay[m];
        z[(size_t)nm[m] * JL + jl] = az[m];
    }
}

// ====== fused L3: gather y2 (D=64) + relu(z2+agg) into LDS, transform 64->32 ======
// grid = NN/32 = 1250 exactly
__global__ __launch_bounds__(256, 4) void fconv3_kernel(
        const float4* __restrict__ y,      // y2: N x 16
        const float4* __restrict__ z,      // z2: N x 16
        const int* __restrict__ rowptr,
        const int* __restrict__ col,
        const float4* __restrict__ Wrel,   // 64 x 8
        const float4* __restrict__ Wroot,  // 64 x 8
        const float4* __restrict__ bias,   // 8
        float4* __restrict__ y3,
        float4* __restrict__ z3, int n) {
    __shared__ float4 sH[32][17];          // h2 tile (+pad)
    __shared__ float4 sR[64 * 8];          // 8 KB
    __shared__ float4 sT[64 * 8];          // 8 KB
    for (int i = threadIdx.x; i < 64 * 8; i += 256) { sR[i] = Wrel[i]; sT[i] = Wroot[i]; }
    int t = threadIdx.x;
    // ---- Phase A: 2 tasks/thread ----
#pragma unroll
    for (int half = 0; half < 2; ++half) {
        int task = t + half * 256;
        int na = task >> 4, c = task & 15;
        int node = blockIdx.x * 32 + na;
        float4 a = z[(size_t)node * 16 + c];
        int beg = rowptr[node], end = rowptr[node + 1];
        int e = beg;
        for (; e + 4 <= end; e += 4) {
            int c0 = col[e], c1 = col[e + 1], c2 = col[e + 2], c3 = col[e + 3];
            float4 v0 = y[(size_t)c0 * 16 + c];
            float4 v1 = y[(size_t)c1 * 16 + c];
            float4 v2 = y[(size_t)c2 * 16 + c];
            float4 v3 = y[(size_t)c3 * 16 + c];
            a.x += (v0.x + v1.x) + (v2.x + v3.x);
            a.y += (v0.y + v1.y) + (v2.y + v3.y);
            a.z += (v0.z + v1.z) + (v2.z + v3.z);
            a.w += (v0.w + v1.w) + (v2.w + v3.w);
        }
        for (; e < end; ++e) {
            float4 v = y[(size_t)col[e] * 16 + c];
            a.x += v.x; a.y += v.y; a.z += v.z; a.w += v.w;
        }
        a.x = fmaxf(a.x, 0.f); a.y = fmaxf(a.y, 0.f);
        a.z = fmaxf(a.z, 0.f); a.w = fmaxf(a.w, 0.f);
        sH[na][c] = a;
    }
    __syncthreads();
    // ---- Phase B: 1 node x 4 outputs per thread ----
    int jl = t & 7, mg = t >> 3;
    int node = blockIdx.x * 32 + mg;
    float4 ay = {0.f, 0.f, 0.f, 0.f};
    float4 az = bias[jl];
#pragma unroll 4
    for (int kc = 0; kc < 16; ++kc) {
        float4 h4 = sH[mg][kc];
#pragma unroll
        for (int tt = 0; tt < 4; ++tt) {
            float hv = fcomp(h4, tt);
            float4 wr = sR[(kc * 4 + tt) * 8 + jl];
            float4 wt = sT[(kc * 4 + tt) * 8 + jl];
            ay.x += hv * wr.x; ay.y += hv * wr.y;
            ay.z += hv * wr.z; ay.w += hv * wr.w;
            az.x += hv * wt.x; az.y += hv * wt.y;
            az.z += hv * wt.z; az.w += hv * wt.w;
        }
    }
    y3[(size_t)node * 8 + jl] = ay;
    z3[(size_t)node * 8 + jl] = az;
}

// ====== fold Wfc into layer-4 weights ======
__global__ void fold_kernel(const float* __restrict__ W4rel,
                            const float* __restrict__ W4root,
                            const float* __restrict__ b4,
                            const float* __restrict__ Wfc,
                            float* __restrict__ wf) {
    int t = threadIdx.x;
    if (t < 32) {
        float a = 0.f, b = 0.f;
#pragma unroll
        for (int j = 0; j < 16; ++j) {
            float w = Wfc[j];
            a += W4rel[t * 16 + j] * w;
            b += W4root[t * 16 + j] * w;
        }
        wf[t] = a;
        wf[32 + t] = b;
    } else if (t == 32) {
        float s = 0.f;
#pragma unroll
        for (int j = 0; j < 16; ++j) s += b4[j] * Wfc[j];
        wf[64] = s;
    }
}

// ====== fused L4: gather y3 (D=32) + relu(z3+agg) into LDS, folded dot -> y4,z4 ======
__global__ __launch_bounds__(256, 4) void fconv4_kernel(
        const float4* __restrict__ y,      // y3: N x 8
        const float4* __restrict__ z,      // z3: N x 8
        const int* __restrict__ rowptr,
        const int* __restrict__ col,
        const float* __restrict__ wf,      // 65
        float* __restrict__ y4,
        float* __restrict__ z4, int n) {
    __shared__ float4 sHT[8][257];         // h3 tile TRANSPOSED (+pad)
    __shared__ float4 sF[8], sRF[8];
    __shared__ float sB;
    if (threadIdx.x < 8) sF[threadIdx.x] = ((const float4*)wf)[threadIdx.x];
    else if (threadIdx.x < 16) sRF[threadIdx.x - 8] = ((const float4*)wf)[threadIdx.x];
    else if (threadIdx.x == 16) sB = wf[64];
    int t = threadIdx.x;
    // ---- Phase A: 8 tasks/thread: 256 nodes x 8 cols ----
#pragma unroll
    for (int q = 0; q < 8; ++q) {
        int task = t + q * 256;
        int na = task >> 3, c = task & 7;
        int node = blockIdx.x * 256 + na;
        if (node < n) {
            float4 a = z[(size_t)node * 8 + c];
            int beg = rowptr[node], end = rowptr[node + 1];
            int e = beg;
            for (; e + 4 <= end; e += 4) {
                int c0 = col[e], c1 = col[e + 1], c2 = col[e + 2], c3 = col[e + 3];
                float4 v0 = y[(size_t)c0 * 8 + c];
                float4 v1 = y[(size_t)c1 * 8 + c];
                float4 v2 = y[(size_t)c2 * 8 + c];
                float4 v3 = y[(size_t)c3 * 8 + c];
                a.x += (v0.x + v1.x) + (v2.x + v3.x);
                a.y += (v0.y + v1.y) + (v2.y + v3.y);
                a.z += (v0.z + v1.z) + (v2.z + v3.z);
                a.w += (v0.w + v1.w) + (v2.w + v3.w);
            }
            for (; e < end; ++e) {
                float4 v = y[(size_t)col[e] * 8 + c];
                a.x += v.x; a.y += v.y; a.z += v.z; a.w += v.w;
            }
            a.x = fmaxf(a.x, 0.f); a.y = fmaxf(a.y, 0.f);
            a.z = fmaxf(a.z, 0.f); a.w = fmaxf(a.w, 0.f);
            sHT[c][na] = a;
        }
    }
    __syncthreads();
    // ---- Phase B: thread-per-node folded dots ----
    int node = blockIdx.x * 256 + t;
    if (node < n) {
        float ay = 0.f, az = 0.f;
#pragma unroll
        for (int kc = 0; kc < 8; ++kc) {
            float4 h4 = sHT[kc][t];
            float4 f = sF[kc], r = sRF[kc];
            ay += h4.x * f.x + h4.y * f.y + h4.z * f.z + h4.w * f.w;
            az += h4.x * r.x + h4.y * r.y + h4.z * r.z + h4.w * r.w;
        }
        y4[node] = ay;
        z4[node] = az + sB;
    }
}

// ====== scalar gather + pool: thread-per-node, per-block LDS graph bins ======
__global__ __launch_bounds__(256) void gpool_kernel(
        const float* __restrict__ y4,
        const float* __restrict__ z4,
        const int* __restrict__ rowptr,
        const int* __restrict__ col,
        const int* __restrict__ batch,
        float* __restrict__ sums,
        float* __restrict__ counts) {
    __shared__ float ls[NG];
    __shared__ float lc[NG];
    if (threadIdx.x < NG) { ls[threadIdx.x] = 0.f; lc[threadIdx.x] = 0.f; }
    __syncthreads();
    int nd = blockIdx.x * 256 + threadIdx.x;
    if (nd < NN) {
        float v = z4[nd];
        int beg = rowptr[nd], end = rowptr[nd + 1];
        int e = beg;
        for (; e + 4 <= end; e += 4) {
            v += (y4[col[e]] + y4[col[e + 1]]) + (y4[col[e + 2]] + y4[col[e + 3]]);
        }
        for (; e < end; ++e) v += y4[col[e]];
        int g = batch[nd];
        atomicAdd(&ls[g], v);
        atomicAdd(&lc[g], 1.f);
    }
    __syncthreads();
    if (threadIdx.x < NG && lc[threadIdx.x] > 0.f) {
        atomicAdd(&sums[threadIdx.x], ls[threadIdx.x]);
        atomicAdd(&counts[threadIdx.x], lc[threadIdx.x]);
    }
}

// ================= finalize =================
__global__ void final_kernel(const float* __restrict__ sums,
                             const float* __restrict__ counts,
                             const float* __restrict__ bfc,
                             float* __restrict__ out) {
    int g = threadIdx.x;
    if (g >= NG) return;
    float c = fmaxf(counts[g], 1.0f);
    out[g] = sums[g] / c + bfc[0];
}

extern "C" void kernel_launch(void* const* d_in, const int* in_sizes, int n_in,
                              void* d_out, int out_size, void* d_ws, size_t ws_size,
                              hipStream_t stream) {
    const float* x       = (const float*)d_in[0];
    const int*   ei      = (const int*)d_in[1];
    const int*   batch   = (const int*)d_in[2];
    const float* W1_rel  = (const float*)d_in[3];
    const float* b1      = (const float*)d_in[4];
    const float* W1_root = (const float*)d_in[5];
    const float* W2_rel  = (const float*)d_in[6];
    const float* b2      = (const float*)d_in[7];
    const float* W2_root = (const float*)d_in[8];
    const float* W3_rel  = (const float*)d_in[9];
    const float* b3      = (const float*)d_in[10];
    const float* W3_root = (const float*)d_in[11];
    const float* W4_rel  = (const float*)d_in[12];
    const float* b4      = (const float*)d_in[13];
    const float* W4_root = (const float*)d_in[14];
    const float* Wfc     = (const float*)d_in[15];
    const float* bfc     = (const float*)d_in[16];
    float* out = (float*)d_out;

    const int* src = ei;        // edge_index[0]
    const int* dst = ei + NE;   // edge_index[1]

    // workspace layout
    float* bufH   = (float*)d_ws;                    // N x 128  (h1)
    float* bufY   = bufH + (size_t)NN * 128;         // N x 64   (y2)
    float* bufZ   = bufY + (size_t)NN * 64;          // N x 64   (z2)
    float* y3     = bufZ + (size_t)NN * 64;          // N x 32
    float* z3     = y3 + (size_t)NN * 32;            // N x 32
    float* y4     = z3 + (size_t)NN * 32;            // N
    float* z4     = y4 + NN;                         // N
    float* wf     = z4 + NN;                         // 65 (pad 68)
    int*   deg    = (int*)(wf + 68);                 // N      -- zeroed block start
    float* sums   = (float*)(deg + NN);              // G
    float* counts = sums + NG;                       // G      -- zeroed block end
    int*   rowptr = (int*)(counts + NG);             // N+1
    int*   cursor = rowptr + NN + 1;                 // N
    int*   col    = cursor + NN;                     // E
    int*   bsum   = col + NE;                        // SCAN_NB

    // ---- one memset zeroes deg + sums + counts ----
    hipMemsetAsync(deg, 0, (size_t)(NN + 2 * NG) * sizeof(int), stream);

    // ---- build CSR (dst-sorted reverse adjacency) ----
    hist_kernel<<<(NE + 255) / 256, 256, 0, stream>>>(dst, deg);
    scan1_kernel<<<SCAN_NB, 256, 0, stream>>>(deg, rowptr, bsum);
    scan2_kernel<<<1, 256, 0, stream>>>(bsum, rowptr);
    scan3_kernel<<<SCAN_NB, 256, 0, stream>>>(rowptr, bsum, cursor);
    fill_kernel<<<(NE + 255) / 256, 256, 0, stream>>>(src, dst, cursor, col);

    // ---- fold Wfc through layer 4 (linear tail) ----
    fold_kernel<<<1, 64, 0, stream>>>(W4_rel, W4_root, b4, Wfc, wf);

    // ---- Layer 1 fused: gather(x) + conv 32->128 ----
    fconv1_kernel<<<NN / 32, 256, 0, stream>>>(
        (const float4*)x, rowptr, col,
        (const float4*)W1_rel, (const float4*)W1_root, (const float4*)b1,
        (float4*)bufH, NN);

    // ---- Layer 2 transform: h1 -> y2, z2 (128 -> 64) ----
    mmyz_kernel<128, 64, 2><<<(NN + 31) / 32, 256, 0, stream>>>(
        (const float4*)bufH, (const float4*)W2_rel, (const float4*)W2_root,
        (const float4*)b2, (float4*)bufY, (float4*)bufZ, NN);

    // ---- Layer 3 fused: gather(y2)+relu(z2+agg) + transform 64->32 ----
    fconv3_kernel<<<NN / 32, 256, 0, stream>>>(
        (const float4*)bufY, (const float4*)bufZ, rowptr, col,
        (const float4*)W3_rel, (const float4*)W3_root, (const float4*)b3,
        (float4*)y3, (float4*)z3, NN);

    // ---- Layer 4 fused: gather(y3)+relu(z3+agg) + folded dot -> y4, z4 ----
    fconv4_kernel<<<(NN + 255) / 256, 256, 0, stream>>>(
        (const float4*)y3, (const float4*)z3, rowptr, col, wf, y4, z4, NN);

    // ---- final gather + pool + FC ----
    gpool_kernel<<<(NN + 255) / 256, 256, 0, stream>>>(
        y4, z4, rowptr, col, batch, sums, counts);
    final_kernel<<<1, 64, 0, stream>>>(sums, counts, bfc, out);
}

// Round 11
// 182.603 us; speedup vs baseline: 1.1566x; 1.1566x over previous
//
#include <hip/hip_runtime.h>

#define NN 40000
#define NE 640000
#define NG 64
#define SCAN_NB ((NN + 255) / 256)   // 157 blocks

__device__ __forceinline__ float fcomp(const float4& v, int t) {
    return t == 0 ? v.x : t == 1 ? v.y : t == 2 ? v.z : v.w;
}

// ================= zero scratch (deg + sums + counts) =================
__global__ __launch_bounds__(256) void zero_kernel(int* __restrict__ p, int n) {
    int i = blockIdx.x * 256 + threadIdx.x;
    if (i < n) p[i] = 0;
}

// ================= CSR build =================
__global__ void hist_kernel(const int* __restrict__ dst, int* __restrict__ deg) {
    int e = blockIdx.x * blockDim.x + threadIdx.x;
    if (e < NE) atomicAdd(&deg[dst[e]], 1);
}

__global__ __launch_bounds__(256) void scan1_kernel(const int* __restrict__ deg,
                                                    int* __restrict__ rowptr,
                                                    int* __restrict__ bsum) {
    __shared__ int ws[4];
    __shared__ int wpre[4];
    int i = blockIdx.x * 256 + threadIdx.x;
    int lane = threadIdx.x & 63, wid = threadIdx.x >> 6;
    int v = (i < NN) ? deg[i] : 0;
    int incl = v;
#pragma unroll
    for (int off = 1; off < 64; off <<= 1) {
        int u = __shfl_up(incl, off, 64);
        if (lane >= off) incl += u;
    }
    if (lane == 63) ws[wid] = incl;
    __syncthreads();
    if (threadIdx.x == 0) {
        int s = 0;
#pragma unroll
        for (int w = 0; w < 4; ++w) { wpre[w] = s; s += ws[w]; }
        bsum[blockIdx.x] = s;
    }
    __syncthreads();
    if (i < NN) rowptr[i] = wpre[wid] + (incl - v);
}

__global__ __launch_bounds__(256) void scan2_kernel(int* __restrict__ bsum,
                                                    int* __restrict__ rowptr) {
    __shared__ int ws[4];
    __shared__ int wpre[4];
    int t = threadIdx.x;
    int lane = t & 63, wid = t >> 6;
    int v = (t < SCAN_NB) ? bsum[t] : 0;
    int incl = v;
#pragma unroll
    for (int off = 1; off < 64; off <<= 1) {
        int u = __shfl_up(incl, off, 64);
        if (lane >= off) incl += u;
    }
    if (lane == 63) ws[wid] = incl;
    __syncthreads();
    if (t == 0) {
        int s = 0;
#pragma unroll
        for (int w = 0; w < 4; ++w) { wpre[w] = s; s += ws[w]; }
        rowptr[NN] = s;
    }
    __syncthreads();
    if (t < SCAN_NB) bsum[t] = wpre[wid] + (incl - v);
}

__global__ __launch_bounds__(256) void scan3_kernel(int* __restrict__ rowptr,
                                                    const int* __restrict__ bsum,
                                                    int* __restrict__ cursor) {
    int i = blockIdx.x * 256 + threadIdx.x;
    if (i < NN) {
        int e = rowptr[i] + bsum[blockIdx.x];
        rowptr[i] = e;
        cursor[i] = e;
    }
}

__global__ void fill_kernel(const int* __restrict__ src, const int* __restrict__ dst,
                            int* __restrict__ cursor, int* __restrict__ col) {
    int e = blockIdx.x * blockDim.x + threadIdx.x;
    if (e < NE) {
        int pos = atomicAdd(&cursor[dst[e]], 1);
        col[pos] = src[e];
    }
}

// ====== fused L1: gather x (D=32) into LDS, then conv1 32->128 ======
// grid = NN/32 = 1250 exactly
__global__ __launch_bounds__(256, 4) void fconv1_kernel(
        const float4* __restrict__ x,      // N x 8
        const int* __restrict__ rowptr,
        const int* __restrict__ col,
        const float4* __restrict__ Wrel,   // 32 x 32
        const float4* __restrict__ Wroot,  // 32 x 32
        const float4* __restrict__ bias,   // 32
        float4* __restrict__ out, int n) { // N x 32
    __shared__ float4 sA[32][9];           // agg tile (+pad)
    __shared__ float4 sR[32 * 32];         // 16 KB
    __shared__ float4 sT[32 * 32];         // 16 KB
    for (int i = threadIdx.x; i < 32 * 32; i += 256) { sR[i] = Wrel[i]; sT[i] = Wroot[i]; }
    int t = threadIdx.x;
    // ---- Phase A: 1 task/thread: (node, c) gather-sum of x ----
    {
        int na = t >> 3, cA = t & 7;
        int node = blockIdx.x * 32 + na;
        int beg = rowptr[node], end = rowptr[node + 1];
        float4 a = {0.f, 0.f, 0.f, 0.f};
        int e = beg;
        for (; e + 4 <= end; e += 4) {
            int c0 = col[e], c1 = col[e + 1], c2 = col[e + 2], c3 = col[e + 3];
            float4 v0 = x[(size_t)c0 * 8 + cA];
            float4 v1 = x[(size_t)c1 * 8 + cA];
            float4 v2 = x[(size_t)c2 * 8 + cA];
            float4 v3 = x[(size_t)c3 * 8 + cA];
            a.x += (v0.x + v1.x) + (v2.x + v3.x);
            a.y += (v0.y + v1.y) + (v2.y + v3.y);
            a.z += (v0.z + v1.z) + (v2.z + v3.z);
            a.w += (v0.w + v1.w) + (v2.w + v3.w);
        }
        for (; e < end; ++e) {
            float4 v = x[(size_t)col[e] * 8 + cA];
            a.x += v.x; a.y += v.y; a.z += v.z; a.w += v.w;
        }
        sA[na][cA] = a;
    }
    __syncthreads();
    // ---- Phase B: 2 nodes x 8 outputs per thread ----
    int jg = t % 16, mg = t / 16;
    int n0 = blockIdx.x * 32 + mg * 2;
    float4 bb0 = bias[2 * jg], bb1 = bias[2 * jg + 1];
    float4 acc00 = bb0, acc01 = bb1, acc10 = bb0, acc11 = bb1;
#pragma unroll 2
    for (int kc = 0; kc < 8; ++kc) {
        float4 a0 = sA[2 * mg][kc];
        float4 a1 = sA[2 * mg + 1][kc];
        float4 x0 = x[(size_t)n0 * 8 + kc];
        float4 x1 = x[(size_t)(n0 + 1) * 8 + kc];
#pragma unroll
        for (int tt = 0; tt < 4; ++tt) {
            int k = kc * 4 + tt;
            float4 wr0 = sR[k * 32 + 2 * jg], wr1 = sR[k * 32 + 2 * jg + 1];
            float4 wt0 = sT[k * 32 + 2 * jg], wt1 = sT[k * 32 + 2 * jg + 1];
            float av0 = fcomp(a0, tt), xv0 = fcomp(x0, tt);
            float av1 = fcomp(a1, tt), xv1 = fcomp(x1, tt);
            acc00.x += av0 * wr0.x + xv0 * wt0.x;
            acc00.y += av0 * wr0.y + xv0 * wt0.y;
            acc00.z += av0 * wr0.z + xv0 * wt0.z;
            acc00.w += av0 * wr0.w + xv0 * wt0.w;
            acc01.x += av0 * wr1.x + xv0 * wt1.x;
            acc01.y += av0 * wr1.y + xv0 * wt1.y;
            acc01.z += av0 * wr1.z + xv0 * wt1.z;
            acc01.w += av0 * wr1.w + xv0 * wt1.w;
            acc10.x += av1 * wr0.x + xv1 * wt0.x;
            acc10.y += av1 * wr0.y + xv1 * wt0.y;
            acc10.z += av1 * wr0.z + xv1 * wt0.z;
            acc10.w += av1 * wr0.w + xv1 * wt0.w;
            acc11.x += av1 * wr1.x + xv1 * wt1.x;
            acc11.y += av1 * wr1.y + xv1 * wt1.y;
            acc11.z += av1 * wr1.z + xv1 * wt1.z;
            acc11.w += av1 * wr1.w + xv1 * wt1.w;
        }
    }
    float4 r;
    r.x = fmaxf(acc00.x, 0.f); r.y = fmaxf(acc00.y, 0.f);
    r.z = fmaxf(acc00.z, 0.f); r.w = fmaxf(acc00.w, 0.f);
    out[(size_t)n0 * 32 + 2 * jg] = r;
    r.x = fmaxf(acc01.x, 0.f); r.y = fmaxf(acc01.y, 0.f);
    r.z = fmaxf(acc01.z, 0.f); r.w = fmaxf(acc01.w, 0.f);
    out[(size_t)n0 * 32 + 2 * jg + 1] = r;
    r.x = fmaxf(acc10.x, 0.f); r.y = fmaxf(acc10.y, 0.f);
    r.z = fmaxf(acc10.z, 0.f); r.w = fmaxf(acc10.w, 0.f);
    out[(size_t)(n0 + 1) * 32 + 2 * jg] = r;
    r.x = fmaxf(acc11.x, 0.f); r.y = fmaxf(acc11.y, 0.f);
    r.z = fmaxf(acc11.z, 0.f); r.w = fmaxf(acc11.w, 0.f);
    out[(size_t)(n0 + 1) * 32 + 2 * jg + 1] = r;
}

// ====== fused transform: y = h@Wrel, z = h@Wroot + b (layer 2, 128->64) ======
template<int K, int DOUT, int NPT>
__global__ __launch_bounds__(256, 6) void mmyz_kernel(
        const float4* __restrict__ h,
        const float4* __restrict__ Wrel,
        const float4* __restrict__ Wroot,
        const float4* __restrict__ bias,
        float4* __restrict__ y,
        float4* __restrict__ z, int n) {
    constexpr int JL = DOUT / 4, MG = 256 / JL, NPB = MG * NPT;
    constexpr int SLAB = (K * JL * 2 * 16 <= 16384) ? K : 32;
    constexpr int NS = K / SLAB;
    __shared__ float4 sR[SLAB * JL];
    __shared__ float4 sT[SLAB * JL];
    int jl = threadIdx.x % JL;
    int mg = threadIdx.x / JL;
    int node0 = blockIdx.x * NPB + mg * NPT;
    int nm[NPT]; bool ok[NPT];
#pragma unroll
    for (int m = 0; m < NPT; ++m) {
        int nd = node0 + m; ok[m] = nd < n; nm[m] = ok[m] ? nd : 0;
    }
    float4 bb = bias[jl];
    float4 ay[NPT], az[NPT];
#pragma unroll
    for (int m = 0; m < NPT; ++m) {
        ay[m].x = 0.f; ay[m].y = 0.f; ay[m].z = 0.f; ay[m].w = 0.f;
        az[m] = bb;
    }
    for (int s = 0; s < NS; ++s) {
        if (NS > 1) __syncthreads();
        for (int i = threadIdx.x; i < SLAB * JL; i += 256) {
            sR[i] = Wrel[s * SLAB * JL + i];
            sT[i] = Wroot[s * SLAB * JL + i];
        }
        __syncthreads();
#pragma unroll 2
        for (int kc = 0; kc < SLAB / 4; ++kc) {
            float4 h4[NPT];
#pragma unroll
            for (int m = 0; m < NPT; ++m)
                h4[m] = h[(size_t)nm[m] * (K / 4) + s * (SLAB / 4) + kc];
#pragma unroll
            for (int tt = 0; tt < 4; ++tt) {
                float4 wr = sR[(kc * 4 + tt) * JL + jl];
                float4 wt = sT[(kc * 4 + tt) * JL + jl];
#pragma unroll
                for (int m = 0; m < NPT; ++m) {
                    float hv = fcomp(h4[m], tt);
                    ay[m].x += hv * wr.x; ay[m].y += hv * wr.y;
                    ay[m].z += hv * wr.z; ay[m].w += hv * wr.w;
                    az[m].x += hv * wt.x; az[m].y += hv * wt.y;
                    az[m].z += hv * wt.z; az[m].w += hv * wt.w;
                }
            }
        }
    }
#pragma unroll
    for (int m = 0; m < NPT; ++m) {
        if (!ok[m]) continue;
        y[(size_t)nm[m] * JL + jl] = ay[m];
        z[(size_t)nm[m] * JL + jl] = az[m];
    }
}

// ====== fused L3: gather y2 (D=64) + relu(z2+agg) into LDS, transform 64->32 ======
// grid = NN/32 = 1250 exactly
__global__ __launch_bounds__(256, 4) void fconv3_kernel(
        const float4* __restrict__ y,      // y2: N x 16
        const float4* __restrict__ z,      // z2: N x 16
        const int* __restrict__ rowptr,
        const int* __restrict__ col,
        const float4* __restrict__ Wrel,   // 64 x 8
        const float4* __restrict__ Wroot,  // 64 x 8
        const float4* __restrict__ bias,   // 8
        float4* __restrict__ y3,
        float4* __restrict__ z3, int n) {
    __shared__ float4 sH[32][17];          // h2 tile (+pad)
    __shared__ float4 sR[64 * 8];          // 8 KB
    __shared__ float4 sT[64 * 8];          // 8 KB
    for (int i = threadIdx.x; i < 64 * 8; i += 256) { sR[i] = Wrel[i]; sT[i] = Wroot[i]; }
    int t = threadIdx.x;
    // ---- Phase A: 2 tasks/thread ----
#pragma unroll
    for (int half = 0; half < 2; ++half) {
        int task = t + half * 256;
        int na = task >> 4, c = task & 15;
        int node = blockIdx.x * 32 + na;
        float4 a = z[(size_t)node * 16 + c];
        int beg = rowptr[node], end = rowptr[node + 1];
        int e = beg;
        for (; e + 4 <= end; e += 4) {
            int c0 = col[e], c1 = col[e + 1], c2 = col[e + 2], c3 = col[e + 3];
            float4 v0 = y[(size_t)c0 * 16 + c];
            float4 v1 = y[(size_t)c1 * 16 + c];
            float4 v2 = y[(size_t)c2 * 16 + c];
            float4 v3 = y[(size_t)c3 * 16 + c];
            a.x += (v0.x + v1.x) + (v2.x + v3.x);
            a.y += (v0.y + v1.y) + (v2.y + v3.y);
            a.z += (v0.z + v1.z) + (v2.z + v3.z);
            a.w += (v0.w + v1.w) + (v2.w + v3.w);
        }
        for (; e < end; ++e) {
            float4 v = y[(size_t)col[e] * 16 + c];
            a.x += v.x; a.y += v.y; a.z += v.z; a.w += v.w;
        }
        a.x = fmaxf(a.x, 0.f); a.y = fmaxf(a.y, 0.f);
        a.z = fmaxf(a.z, 0.f); a.w = fmaxf(a.w, 0.f);
        sH[na][c] = a;
    }
    __syncthreads();
    // ---- Phase B: 1 node x 4 outputs per thread ----
    int jl = t & 7, mg = t >> 3;
    int node = blockIdx.x * 32 + mg;
    float4 ay = {0.f, 0.f, 0.f, 0.f};
    float4 az = bias[jl];
#pragma unroll 4
    for (int kc = 0; kc < 16; ++kc) {
        float4 h4 = sH[mg][kc];
#pragma unroll
        for (int tt = 0; tt < 4; ++tt) {
            float hv = fcomp(h4, tt);
            float4 wr = sR[(kc * 4 + tt) * 8 + jl];
            float4 wt = sT[(kc * 4 + tt) * 8 + jl];
            ay.x += hv * wr.x; ay.y += hv * wr.y;
            ay.z += hv * wr.z; ay.w += hv * wr.w;
            az.x += hv * wt.x; az.y += hv * wt.y;
            az.z += hv * wt.z; az.w += hv * wt.w;
        }
    }
    y3[(size_t)node * 8 + jl] = ay;
    z3[(size_t)node * 8 + jl] = az;
}

// ====== fold Wfc into layer-4 weights ======
__global__ void fold_kernel(const float* __restrict__ W4rel,
                            const float* __restrict__ W4root,
                            const float* __restrict__ b4,
                            const float* __restrict__ Wfc,
                            float* __restrict__ wf) {
    int t = threadIdx.x;
    if (t < 32) {
        float a = 0.f, b = 0.f;
#pragma unroll
        for (int j = 0; j < 16; ++j) {
            float w = Wfc[j];
            a += W4rel[t * 16 + j] * w;
            b += W4root[t * 16 + j] * w;
        }
        wf[t] = a;
        wf[32 + t] = b;
    } else if (t == 32) {
        float s = 0.f;
#pragma unroll
        for (int j = 0; j < 16; ++j) s += b4[j] * Wfc[j];
        wf[64] = s;
    }
}

// ====== fused L4: gather y3 (D=32) + relu(z3+agg), folded dot -> y4, z4 ======
// grid = NN/32 = 1250; Phase A = one (node,col) gather per thread (like gatherz<8>)
__global__ __launch_bounds__(256, 8) void fconv4_kernel(
        const float4* __restrict__ y,      // y3: N x 8
        const float4* __restrict__ z,      // z3: N x 8
        const int* __restrict__ rowptr,
        const int* __restrict__ col,
        const float* __restrict__ wf,      // 65
        float* __restrict__ y4,
        float* __restrict__ z4, int n) {
    __shared__ float4 sH[32][9];           // h3 tile (+pad)
    __shared__ float4 sF[8], sRF[8];
    __shared__ float sB;
    if (threadIdx.x < 8) sF[threadIdx.x] = ((const float4*)wf)[threadIdx.x];
    else if (threadIdx.x < 16) sRF[threadIdx.x - 8] = ((const float4*)wf)[threadIdx.x];
    else if (threadIdx.x == 16) sB = wf[64];
    int t = threadIdx.x;
    // ---- Phase A: one (node, col) gather per thread ----
    {
        int na = t >> 3, c = t & 7;
        int node = blockIdx.x * 32 + na;
        float4 a = z[(size_t)node * 8 + c];
        int beg = rowptr[node], end = rowptr[node + 1];
        int e = beg;
        for (; e + 4 <= end; e += 4) {
            int c0 = col[e], c1 = col[e + 1], c2 = col[e + 2], c3 = col[e + 3];
            float4 v0 = y[(size_t)c0 * 8 + c];
            float4 v1 = y[(size_t)c1 * 8 + c];
            float4 v2 = y[(size_t)c2 * 8 + c];
            float4 v3 = y[(size_t)c3 * 8 + c];
            a.x += (v0.x + v1.x) + (v2.x + v3.x);
            a.y += (v0.y + v1.y) + (v2.y + v3.y);
            a.z += (v0.z + v1.z) + (v2.z + v3.z);
            a.w += (v0.w + v1.w) + (v2.w + v3.w);
        }
        for (; e < end; ++e) {
            float4 v = y[(size_t)col[e] * 8 + c];
            a.x += v.x; a.y += v.y; a.z += v.z; a.w += v.w;
        }
        a.x = fmaxf(a.x, 0.f); a.y = fmaxf(a.y, 0.f);
        a.z = fmaxf(a.z, 0.f); a.w = fmaxf(a.w, 0.f);
        sH[na][c] = a;
    }
    __syncthreads();
    // ---- Phase B: 32 threads do the folded dots ----
    if (t < 32) {
        int nd = blockIdx.x * 32 + t;
        float ay = 0.f, az = 0.f;
#pragma unroll
        for (int kc = 0; kc < 8; ++kc) {
            float4 h4 = sH[t][kc];
            float4 f = sF[kc], r = sRF[kc];
            ay += h4.x * f.x + h4.y * f.y + h4.z * f.z + h4.w * f.w;
            az += h4.x * r.x + h4.y * r.y + h4.z * r.z + h4.w * r.w;
        }
        y4[nd] = ay;
        z4[nd] = az + sB;
    }
}

// ====== scalar gather + pool: thread-per-node, per-block LDS graph bins ======
__global__ __launch_bounds__(256) void gpool_kernel(
        const float* __restrict__ y4,
        const float* __restrict__ z4,
        const int* __restrict__ rowptr,
        const int* __restrict__ col,
        const int* __restrict__ batch,
        float* __restrict__ sums,
        float* __restrict__ counts) {
    __shared__ float ls[NG];
    __shared__ float lc[NG];
    if (threadIdx.x < NG) { ls[threadIdx.x] = 0.f; lc[threadIdx.x] = 0.f; }
    __syncthreads();
    int nd = blockIdx.x * 256 + threadIdx.x;
    if (nd < NN) {
        float v = z4[nd];
        int beg = rowptr[nd], end = rowptr[nd + 1];
        int e = beg;
        for (; e + 4 <= end; e += 4) {
            v += (y4[col[e]] + y4[col[e + 1]]) + (y4[col[e + 2]] + y4[col[e + 3]]);
        }
        for (; e < end; ++e) v += y4[col[e]];
        int g = batch[nd];
        atomicAdd(&ls[g], v);
        atomicAdd(&lc[g], 1.f);
    }
    __syncthreads();
    if (threadIdx.x < NG && lc[threadIdx.x] > 0.f) {
        atomicAdd(&sums[threadIdx.x], ls[threadIdx.x]);
        atomicAdd(&counts[threadIdx.x], lc[threadIdx.x]);
    }
}

// ================= finalize =================
__global__ void final_kernel(const float* __restrict__ sums,
                             const float* __restrict__ counts,
                             const float* __restrict__ bfc,
                             float* __restrict__ out) {
    int g = threadIdx.x;
    if (g >= NG) return;
    float c = fmaxf(counts[g], 1.0f);
    out[g] = sums[g] / c + bfc[0];
}

extern "C" void kernel_launch(void* const* d_in, const int* in_sizes, int n_in,
                              void* d_out, int out_size, void* d_ws, size_t ws_size,
                              hipStream_t stream) {
    const float* x       = (const float*)d_in[0];
    const int*   ei      = (const int*)d_in[1];
    const int*   batch   = (const int*)d_in[2];
    const float* W1_rel  = (const float*)d_in[3];
    const float* b1      = (const float*)d_in[4];
    const float* W1_root = (const float*)d_in[5];
    const float* W2_rel  = (const float*)d_in[6];
    const float* b2      = (const float*)d_in[7];
    const float* W2_root = (const float*)d_in[8];
    const float* W3_rel  = (const float*)d_in[9];
    const float* b3      = (const float*)d_in[10];
    const float* W3_root = (const float*)d_in[11];
    const float* W4_rel  = (const float*)d_in[12];
    const float* b4      = (const float*)d_in[13];
    const float* W4_root = (const float*)d_in[14];
    const float* Wfc     = (const float*)d_in[15];
    const float* bfc     = (const float*)d_in[16];
    float* out = (float*)d_out;

    const int* src = ei;        // edge_index[0]
    const int* dst = ei + NE;   // edge_index[1]

    // workspace layout
    float* bufH   = (float*)d_ws;                    // N x 128  (h1)
    float* bufY   = bufH + (size_t)NN * 128;         // N x 64   (y2)
    float* bufZ   = bufY + (size_t)NN * 64;          // N x 64   (z2)
    float* y3     = bufZ + (size_t)NN * 64;          // N x 32
    float* z3     = y3 + (size_t)NN * 32;            // N x 32
    float* y4     = z3 + (size_t)NN * 32;            // N
    float* z4     = y4 + NN;                         // N
    float* wf     = z4 + NN;                         // 65 (pad 68)
    int*   deg    = (int*)(wf + 68);                 // N      -- zeroed block start
    float* sums   = (float*)(deg + NN);              // G
    float* counts = sums + NG;                       // G      -- zeroed block end
    int*   rowptr = (int*)(counts + NG);             // N+1
    int*   cursor = rowptr + NN + 1;                 // N
    int*   col    = cursor + NN;                     // E
    int*   bsum   = col + NE;                        // SCAN_NB

    // ---- zero deg + sums + counts with our own kernel (rocclr fill is ~43us!) ----
    zero_kernel<<<(NN + 2 * NG + 255) / 256, 256, 0, stream>>>(deg, NN + 2 * NG);

    // ---- build CSR (dst-sorted reverse adjacency) ----
    hist_kernel<<<(NE + 255) / 256, 256, 0, stream>>>(dst, deg);
    scan1_kernel<<<SCAN_NB, 256, 0, stream>>>(deg, rowptr, bsum);
    scan2_kernel<<<1, 256, 0, stream>>>(bsum, rowptr);
    scan3_kernel<<<SCAN_NB, 256, 0, stream>>>(rowptr, bsum, cursor);
    fill_kernel<<<(NE + 255) / 256, 256, 0, stream>>>(src, dst, cursor, col);

    // ---- fold Wfc through layer 4 (linear tail) ----
    fold_kernel<<<1, 64, 0, stream>>>(W4_rel, W4_root, b4, Wfc, wf);

    // ---- Layer 1 fused: gather(x) + conv 32->128 ----
    fconv1_kernel<<<NN / 32, 256, 0, stream>>>(
        (const float4*)x, rowptr, col,
        (const float4*)W1_rel, (const float4*)W1_root, (const float4*)b1,
        (float4*)bufH, NN);

    // ---- Layer 2 transform: h1 -> y2, z2 (128 -> 64) ----
    mmyz_kernel<128, 64, 2><<<(NN + 31) / 32, 256, 0, stream>>>(
        (const float4*)bufH, (const float4*)W2_rel, (const float4*)W2_root,
        (const float4*)b2, (float4*)bufY, (float4*)bufZ, NN);

    // ---- Layer 3 fused: gather(y2)+relu(z2+agg) + transform 64->32 ----
    fconv3_kernel<<<NN / 32, 256, 0, stream>>>(
        (const float4*)bufY, (const float4*)bufZ, rowptr, col,
        (const float4*)W3_rel, (const float4*)W3_root, (const float4*)b3,
        (float4*)y3, (float4*)z3, NN);

    // ---- Layer 4 fused: gather(y3)+relu(z3+agg) + folded dot -> y4, z4 ----
    fconv4_kernel<<<NN / 32, 256, 0, stream>>>(
        (const float4*)y3, (const float4*)z3, rowptr, col, wf, y4, z4, NN);

    // ---- final gather + pool + FC ----
    gpool_kernel<<<(NN + 255) / 256, 256, 0, stream>>>(
        y4, z4, rowptr, col, batch, sums, counts);
    final_kernel<<<1, 64, 0, stream>>>(sums, counts, bfc, out);
}

// Round 12
// 181.116 us; speedup vs baseline: 1.1661x; 1.0082x over previous
//
#include <hip/hip_runtime.h>

#define NN 40000
#define NE 640000
#define NG 64
#define SCAN_NB ((NN + 255) / 256)   // 157 blocks

__device__ __forceinline__ float fcomp(const float4& v, int t) {
    return t == 0 ? v.x : t == 1 ? v.y : t == 2 ? v.z : v.w;
}

// ========== zero scratch (deg+sums+counts) + fold Wfc through layer 4 ==========
__global__ __launch_bounds__(256) void zero_fold_kernel(
        int* __restrict__ p, int n,
        const float* __restrict__ W4rel,
        const float* __restrict__ W4root,
        const float* __restrict__ b4,
        const float* __restrict__ Wfc,
        float* __restrict__ wf) {
    int i = blockIdx.x * 256 + threadIdx.x;
    if (i < n) p[i] = 0;
    if (blockIdx.x == 0) {
        int t = threadIdx.x;
        if (t < 32) {
            float a = 0.f, b = 0.f;
#pragma unroll
            for (int j = 0; j < 16; ++j) {
                float w = Wfc[j];
                a += W4rel[t * 16 + j] * w;
                b += W4root[t * 16 + j] * w;
            }
            wf[t] = a;
            wf[32 + t] = b;
        } else if (t == 32) {
            float s = 0.f;
#pragma unroll
            for (int j = 0; j < 16; ++j) s += b4[j] * Wfc[j];
            wf[64] = s;
        }
    }
}

// ================= CSR build =================
__global__ void hist_kernel(const int* __restrict__ dst, int* __restrict__ deg) {
    int e = blockIdx.x * blockDim.x + threadIdx.x;
    if (e < NE) atomicAdd(&deg[dst[e]], 1);
}

__global__ __launch_bounds__(256) void scan1_kernel(const int* __restrict__ deg,
                                                    int* __restrict__ rowptr,
                                                    int* __restrict__ bsum) {
    __shared__ int ws[4];
    __shared__ int wpre[4];
    int i = blockIdx.x * 256 + threadIdx.x;
    int lane = threadIdx.x & 63, wid = threadIdx.x >> 6;
    int v = (i < NN) ? deg[i] : 0;
    int incl = v;
#pragma unroll
    for (int off = 1; off < 64; off <<= 1) {
        int u = __shfl_up(incl, off, 64);
        if (lane >= off) incl += u;
    }
    if (lane == 63) ws[wid] = incl;
    __syncthreads();
    if (threadIdx.x == 0) {
        int s = 0;
#pragma unroll
        for (int w = 0; w < 4; ++w) { wpre[w] = s; s += ws[w]; }
        bsum[blockIdx.x] = s;
    }
    __syncthreads();
    if (i < NN) rowptr[i] = wpre[wid] + (incl - v);
}

__global__ __launch_bounds__(256) void scan2_kernel(int* __restrict__ bsum,
                                                    int* __restrict__ rowptr) {
    __shared__ int ws[4];
    __shared__ int wpre[4];
    int t = threadIdx.x;
    int lane = t & 63, wid = t >> 6;
    int v = (t < SCAN_NB) ? bsum[t] : 0;
    int incl = v;
#pragma unroll
    for (int off = 1; off < 64; off <<= 1) {
        int u = __shfl_up(incl, off, 64);
        if (lane >= off) incl += u;
    }
    if (lane == 63) ws[wid] = incl;
    __syncthreads();
    if (t == 0) {
        int s = 0;
#pragma unroll
        for (int w = 0; w < 4; ++w) { wpre[w] = s; s += ws[w]; }
        rowptr[NN] = s;
    }
    __syncthreads();
    if (t < SCAN_NB) bsum[t] = wpre[wid] + (incl - v);
}

__global__ __launch_bounds__(256) void scan3_kernel(int* __restrict__ rowptr,
                                                    const int* __restrict__ bsum,
                                                    int* __restrict__ cursor) {
    int i = blockIdx.x * 256 + threadIdx.x;
    if (i < NN) {
        int e = rowptr[i] + bsum[blockIdx.x];
        rowptr[i] = e;
        cursor[i] = e;
    }
}

__global__ void fill_kernel(const int* __restrict__ src, const int* __restrict__ dst,
                            int* __restrict__ cursor, int* __restrict__ col) {
    int e = blockIdx.x * blockDim.x + threadIdx.x;
    if (e < NE) {
        int pos = atomicAdd(&cursor[dst[e]], 1);
        col[pos] = src[e];
    }
}

// ====== fused L1+L2: gather x -> h1 in LDS -> y2,z2 (h1 never hits memory) ======
// grid = NN/32 = 1250 exactly. LDS = 53.0 KB -> 3 blocks/CU.
__global__ __launch_bounds__(256, 3) void fconv12_kernel(
        const float4* __restrict__ x,       // N x 8
        const int* __restrict__ rowptr,
        const int* __restrict__ col,
        const float4* __restrict__ W1rel,   // 32 x 32
        const float4* __restrict__ W1root,  // 32 x 32
        const float4* __restrict__ b1,      // 32
        const float4* __restrict__ W2rel,   // 128 x 16
        const float4* __restrict__ W2root,  // 128 x 16
        const float4* __restrict__ b2,      // 16
        float4* __restrict__ y2,
        float4* __restrict__ z2) {
    __shared__ float4 sA[32][9];            // gathered-x tile (+pad)     4.5 KB
    __shared__ float4 sH[32][33];           // h1 tile (+pad)            16.5 KB
    __shared__ float4 sWa[32 * 32];         // W1rel, then W2rel slabs     16 KB
    __shared__ float4 sWb[32 * 32];         // W1root, then W2root slabs   16 KB
    int t = threadIdx.x;
    for (int i = t; i < 32 * 32; i += 256) { sWa[i] = W1rel[i]; sWb[i] = W1root[i]; }
    // ---- Phase A: gather x into sA (one (node,col) per thread) ----
    {
        int na = t >> 3, cA = t & 7;
        int node = blockIdx.x * 32 + na;
        int beg = rowptr[node], end = rowptr[node + 1];
        float4 a = {0.f, 0.f, 0.f, 0.f};
        int e = beg;
        for (; e + 4 <= end; e += 4) {
            int c0 = col[e], c1 = col[e + 1], c2 = col[e + 2], c3 = col[e + 3];
            float4 v0 = x[(size_t)c0 * 8 + cA];
            float4 v1 = x[(size_t)c1 * 8 + cA];
            float4 v2 = x[(size_t)c2 * 8 + cA];
            float4 v3 = x[(size_t)c3 * 8 + cA];
            a.x += (v0.x + v1.x) + (v2.x + v3.x);
            a.y += (v0.y + v1.y) + (v2.y + v3.y);
            a.z += (v0.z + v1.z) + (v2.z + v3.z);
            a.w += (v0.w + v1.w) + (v2.w + v3.w);
        }
        for (; e < end; ++e) {
            float4 v = x[(size_t)col[e] * 8 + cA];
            a.x += v.x; a.y += v.y; a.z += v.z; a.w += v.w;
        }
        sA[na][cA] = a;
    }
    __syncthreads();
    // ---- Phase B1: h1 = relu(agg@W1rel + x@W1root + b1) -> sH ----
    {
        int mg = t & 15, jg = t >> 4;       // node-pair, col-pair
        int n0 = blockIdx.x * 32 + 2 * mg;
        float4 bb0 = b1[2 * jg], bb1 = b1[2 * jg + 1];
        float4 acc00 = bb0, acc01 = bb1, acc10 = bb0, acc11 = bb1;
#pragma unroll 2
        for (int kc = 0; kc < 8; ++kc) {
            float4 a0 = sA[2 * mg][kc];
            float4 a1 = sA[2 * mg + 1][kc];
            float4 x0 = x[(size_t)n0 * 8 + kc];
            float4 x1 = x[(size_t)(n0 + 1) * 8 + kc];
#pragma unroll
            for (int tt = 0; tt < 4; ++tt) {
                int k = kc * 4 + tt;
                float4 wr0 = sWa[k * 32 + 2 * jg], wr1 = sWa[k * 32 + 2 * jg + 1];
                float4 wt0 = sWb[k * 32 + 2 * jg], wt1 = sWb[k * 32 + 2 * jg + 1];
                float av0 = fcomp(a0, tt), xv0 = fcomp(x0, tt);
                float av1 = fcomp(a1, tt), xv1 = fcomp(x1, tt);
                acc00.x += av0 * wr0.x + xv0 * wt0.x;
                acc00.y += av0 * wr0.y + xv0 * wt0.y;
                acc00.z += av0 * wr0.z + xv0 * wt0.z;
                acc00.w += av0 * wr0.w + xv0 * wt0.w;
                acc01.x += av0 * wr1.x + xv0 * wt1.x;
                acc01.y += av0 * wr1.y + xv0 * wt1.y;
                acc01.z += av0 * wr1.z + xv0 * wt1.z;
                acc01.w += av0 * wr1.w + xv0 * wt1.w;
                acc10.x += av1 * wr0.x + xv1 * wt0.x;
                acc10.y += av1 * wr0.y + xv1 * wt0.y;
                acc10.z += av1 * wr0.z + xv1 * wt0.z;
                acc10.w += av1 * wr0.w + xv1 * wt0.w;
                acc11.x += av1 * wr1.x + xv1 * wt1.x;
                acc11.y += av1 * wr1.y + xv1 * wt1.y;
                acc11.z += av1 * wr1.z + xv1 * wt1.z;
                acc11.w += av1 * wr1.w + xv1 * wt1.w;
            }
        }
        float4 r;
        r.x = fmaxf(acc00.x, 0.f); r.y = fmaxf(acc00.y, 0.f);
        r.z = fmaxf(acc00.z, 0.f); r.w = fmaxf(acc00.w, 0.f);
        sH[2 * mg][2 * jg] = r;
        r.x = fmaxf(acc01.x, 0.f); r.y = fmaxf(acc01.y, 0.f);
        r.z = fmaxf(acc01.z, 0.f); r.w = fmaxf(acc01.w, 0.f);
        sH[2 * mg][2 * jg + 1] = r;
        r.x = fmaxf(acc10.x, 0.f); r.y = fmaxf(acc10.y, 0.f);
        r.z = fmaxf(acc10.z, 0.f); r.w = fmaxf(acc10.w, 0.f);
        sH[2 * mg + 1][2 * jg] = r;
        r.x = fmaxf(acc11.x, 0.f); r.y = fmaxf(acc11.y, 0.f);
        r.z = fmaxf(acc11.z, 0.f); r.w = fmaxf(acc11.w, 0.f);
        sH[2 * mg + 1][2 * jg + 1] = r;
    }
    // ---- Phase B2: y2 = h1@W2rel, z2 = h1@W2root + b2, 4 K-slabs of 32 ----
    int na0 = t >> 4, na1 = na0 + 16, c = t & 15;
    float4 bb = b2[c];
    float4 ay0 = {0.f, 0.f, 0.f, 0.f}, ay1 = {0.f, 0.f, 0.f, 0.f};
    float4 az0 = bb, az1 = bb;
    for (int s = 0; s < 4; ++s) {
        __syncthreads();                    // prev slab (or B1 weight-use) done
        for (int i = t; i < 512; i += 256) {
            sWa[i] = W2rel[s * 512 + i];
            sWb[i] = W2root[s * 512 + i];
        }
        __syncthreads();
#pragma unroll 2
        for (int kc = 0; kc < 8; ++kc) {
            float4 h0 = sH[na0][s * 8 + kc];
            float4 h1 = sH[na1][s * 8 + kc];
#pragma unroll
            for (int tt = 0; tt < 4; ++tt) {
                float4 wr = sWa[(kc * 4 + tt) * 16 + c];
                float4 wt = sWb[(kc * 4 + tt) * 16 + c];
                float hv0 = fcomp(h0, tt), hv1 = fcomp(h1, tt);
                ay0.x += hv0 * wr.x; ay0.y += hv0 * wr.y;
                ay0.z += hv0 * wr.z; ay0.w += hv0 * wr.w;
                az0.x += hv0 * wt.x; az0.y += hv0 * wt.y;
                az0.z += hv0 * wt.z; az0.w += hv0 * wt.w;
                ay1.x += hv1 * wr.x; ay1.y += hv1 * wr.y;
                ay1.z += hv1 * wr.z; ay1.w += hv1 * wr.w;
                az1.x += hv1 * wt.x; az1.y += hv1 * wt.y;
                az1.z += hv1 * wt.z; az1.w += hv1 * wt.w;
            }
        }
    }
    int nd0 = blockIdx.x * 32 + na0;
    int nd1 = blockIdx.x * 32 + na1;
    y2[(size_t)nd0 * 16 + c] = ay0;
    z2[(size_t)nd0 * 16 + c] = az0;
    y2[(size_t)nd1 * 16 + c] = ay1;
    z2[(size_t)nd1 * 16 + c] = az1;
}

// ====== fused L3: gather y2 (D=64) + relu(z2+agg) into LDS, transform 64->32 ======
// grid = NN/32 = 1250 exactly
__global__ __launch_bounds__(256, 4) void fconv3_kernel(
        const float4* __restrict__ y,      // y2: N x 16
        const float4* __restrict__ z,      // z2: N x 16
        const int* __restrict__ rowptr,
        const int* __restrict__ col,
        const float4* __restrict__ Wrel,   // 64 x 8
        const float4* __restrict__ Wroot,  // 64 x 8
        const float4* __restrict__ bias,   // 8
        float4* __restrict__ y3,
        float4* __restrict__ z3, int n) {
    __shared__ float4 sH[32][17];          // h2 tile (+pad)
    __shared__ float4 sR[64 * 8];          // 8 KB
    __shared__ float4 sT[64 * 8];          // 8 KB
    for (int i = threadIdx.x; i < 64 * 8; i += 256) { sR[i] = Wrel[i]; sT[i] = Wroot[i]; }
    int t = threadIdx.x;
#pragma unroll
    for (int half = 0; half < 2; ++half) {
        int task = t + half * 256;
        int na = task >> 4, c = task & 15;
        int node = blockIdx.x * 32 + na;
        float4 a = z[(size_t)node * 16 + c];
        int beg = rowptr[node], end = rowptr[node + 1];
        int e = beg;
        for (; e + 4 <= end; e += 4) {
            int c0 = col[e], c1 = col[e + 1], c2 = col[e + 2], c3 = col[e + 3];
            float4 v0 = y[(size_t)c0 * 16 + c];
            float4 v1 = y[(size_t)c1 * 16 + c];
            float4 v2 = y[(size_t)c2 * 16 + c];
            float4 v3 = y[(size_t)c3 * 16 + c];
            a.x += (v0.x + v1.x) + (v2.x + v3.x);
            a.y += (v0.y + v1.y) + (v2.y + v3.y);
            a.z += (v0.z + v1.z) + (v2.z + v3.z);
            a.w += (v0.w + v1.w) + (v2.w + v3.w);
        }
        for (; e < end; ++e) {
            float4 v = y[(size_t)col[e] * 16 + c];
            a.x += v.x; a.y += v.y; a.z += v.z; a.w += v.w;
        }
        a.x = fmaxf(a.x, 0.f); a.y = fmaxf(a.y, 0.f);
        a.z = fmaxf(a.z, 0.f); a.w = fmaxf(a.w, 0.f);
        sH[na][c] = a;
    }
    __syncthreads();
    int jl = t & 7, mg = t >> 3;
    int node = blockIdx.x * 32 + mg;
    float4 ay = {0.f, 0.f, 0.f, 0.f};
    float4 az = bias[jl];
#pragma unroll 4
    for (int kc = 0; kc < 16; ++kc) {
        float4 h4 = sH[mg][kc];
#pragma unroll
        for (int tt = 0; tt < 4; ++tt) {
            float hv = fcomp(h4, tt);
            float4 wr = sR[(kc * 4 + tt) * 8 + jl];
            float4 wt = sT[(kc * 4 + tt) * 8 + jl];
            ay.x += hv * wr.x; ay.y += hv * wr.y;
            ay.z += hv * wr.z; ay.w += hv * wr.w;
            az.x += hv * wt.x; az.y += hv * wt.y;
            az.z += hv * wt.z; az.w += hv * wt.w;
        }
    }
    y3[(size_t)node * 8 + jl] = ay;
    z3[(size_t)node * 8 + jl] = az;
}

// ====== fused L4: gather y3 (D=32) + relu(z3+agg), folded dot -> y4, z4 ======
__global__ __launch_bounds__(256, 8) void fconv4_kernel(
        const float4* __restrict__ y,      // y3: N x 8
        const float4* __restrict__ z,      // z3: N x 8
        const int* __restrict__ rowptr,
        const int* __restrict__ col,
        const float* __restrict__ wf,      // 65
        float* __restrict__ y4,
        float* __restrict__ z4, int n) {
    __shared__ float4 sH[32][9];           // h3 tile (+pad)
    __shared__ float4 sF[8], sRF[8];
    __shared__ float sB;
    if (threadIdx.x < 8) sF[threadIdx.x] = ((const float4*)wf)[threadIdx.x];
    else if (threadIdx.x < 16) sRF[threadIdx.x - 8] = ((const float4*)wf)[threadIdx.x];
    else if (threadIdx.x == 16) sB = wf[64];
    int t = threadIdx.x;
    {
        int na = t >> 3, c = t & 7;
        int node = blockIdx.x * 32 + na;
        float4 a = z[(size_t)node * 8 + c];
        int beg = rowptr[node], end = rowptr[node + 1];
        int e = beg;
        for (; e + 4 <= end; e += 4) {
            int c0 = col[e], c1 = col[e + 1], c2 = col[e + 2], c3 = col[e + 3];
            float4 v0 = y[(size_t)c0 * 8 + c];
            float4 v1 = y[(size_t)c1 * 8 + c];
            float4 v2 = y[(size_t)c2 * 8 + c];
            float4 v3 = y[(size_t)c3 * 8 + c];
            a.x += (v0.x + v1.x) + (v2.x + v3.x);
            a.y += (v0.y + v1.y) + (v2.y + v3.y);
            a.z += (v0.z + v1.z) + (v2.z + v3.z);
            a.w += (v0.w + v1.w) + (v2.w + v3.w);
        }
        for (; e < end; ++e) {
            float4 v = y[(size_t)col[e] * 8 + c];
            a.x += v.x; a.y += v.y; a.z += v.z; a.w += v.w;
        }
        a.x = fmaxf(a.x, 0.f); a.y = fmaxf(a.y, 0.f);
        a.z = fmaxf(a.z, 0.f); a.w = fmaxf(a.w, 0.f);
        sH[na][c] = a;
    }
    __syncthreads();
    if (t < 32) {
        int nd = blockIdx.x * 32 + t;
        float ay = 0.f, az = 0.f;
#pragma unroll
        for (int kc = 0; kc < 8; ++kc) {
            float4 h4 = sH[t][kc];
            float4 f = sF[kc], r = sRF[kc];
            ay += h4.x * f.x + h4.y * f.y + h4.z * f.z + h4.w * f.w;
            az += h4.x * r.x + h4.y * r.y + h4.z * r.z + h4.w * r.w;
        }
        y4[nd] = ay;
        z4[nd] = az + sB;
    }
}

// ====== scalar gather + pool: thread-per-node, per-block LDS graph bins ======
__global__ __launch_bounds__(256) void gpool_kernel(
        const float* __restrict__ y4,
        const float* __restrict__ z4,
        const int* __restrict__ rowptr,
        const int* __restrict__ col,
        const int* __restrict__ batch,
        float* __restrict__ sums,
        float* __restrict__ counts) {
    __shared__ float ls[NG];
    __shared__ float lc[NG];
    if (threadIdx.x < NG) { ls[threadIdx.x] = 0.f; lc[threadIdx.x] = 0.f; }
    __syncthreads();
    int nd = blockIdx.x * 256 + threadIdx.x;
    if (nd < NN) {
        float v = z4[nd];
        int beg = rowptr[nd], end = rowptr[nd + 1];
        int e = beg;
        for (; e + 4 <= end; e += 4) {
            v += (y4[col[e]] + y4[col[e + 1]]) + (y4[col[e + 2]] + y4[col[e + 3]]);
        }
        for (; e < end; ++e) v += y4[col[e]];
        int g = batch[nd];
        atomicAdd(&ls[g], v);
        atomicAdd(&lc[g], 1.f);
    }
    __syncthreads();
    if (threadIdx.x < NG && lc[threadIdx.x] > 0.f) {
        atomicAdd(&sums[threadIdx.x], ls[threadIdx.x]);
        atomicAdd(&counts[threadIdx.x], lc[threadIdx.x]);
    }
}

// ================= finalize =================
__global__ void final_kernel(const float* __restrict__ sums,
                             const float* __restrict__ counts,
                             const float* __restrict__ bfc,
                             float* __restrict__ out) {
    int g = threadIdx.x;
    if (g >= NG) return;
    float c = fmaxf(counts[g], 1.0f);
    out[g] = sums[g] / c + bfc[0];
}

extern "C" void kernel_launch(void* const* d_in, const int* in_sizes, int n_in,
                              void* d_out, int out_size, void* d_ws, size_t ws_size,
                              hipStream_t stream) {
    const float* x       = (const float*)d_in[0];
    const int*   ei      = (const int*)d_in[1];
    const int*   batch   = (const int*)d_in[2];
    const float* W1_rel  = (const float*)d_in[3];
    const float* b1      = (const float*)d_in[4];
    const float* W1_root = (const float*)d_in[5];
    const float* W2_rel  = (const float*)d_in[6];
    const float* b2      = (const float*)d_in[7];
    const float* W2_root = (const float*)d_in[8];
    const float* W3_rel  = (const float*)d_in[9];
    const float* b3      = (const float*)d_in[10];
    const float* W3_root = (const float*)d_in[11];
    const float* W4_rel  = (const float*)d_in[12];
    const float* b4      = (const float*)d_in[13];
    const float* W4_root = (const float*)d_in[14];
    const float* Wfc     = (const float*)d_in[15];
    const float* bfc     = (const float*)d_in[16];
    float* out = (float*)d_out;

    const int* src = ei;        // edge_index[0]
    const int* dst = ei + NE;   // edge_index[1]

    // workspace layout
    float* bufY   = (float*)d_ws;                    // N x 64   (y2)
    float* bufZ   = bufY + (size_t)NN * 64;          // N x 64   (z2)
    float* y3     = bufZ + (size_t)NN * 64;          // N x 32
    float* z3     = y3 + (size_t)NN * 32;            // N x 32
    float* y4     = z3 + (size_t)NN * 32;            // N
    float* z4     = y4 + NN;                         // N
    float* wf     = z4 + NN;                         // 65 (pad 68)
    int*   deg    = (int*)(wf + 68);                 // N      -- zeroed block start
    float* sums   = (float*)(deg + NN);              // G
    float* counts = sums + NG;                       // G      -- zeroed block end
    int*   rowptr = (int*)(counts + NG);             // N+1
    int*   cursor = rowptr + NN + 1;                 // N
    int*   col    = cursor + NN;                     // E
    int*   bsum   = col + NE;                        // SCAN_NB

    // ---- zero deg+sums+counts AND fold Wfc (one launch) ----
    zero_fold_kernel<<<(NN + 2 * NG + 255) / 256, 256, 0, stream>>>(
        deg, NN + 2 * NG, W4_rel, W4_root, b4, Wfc, wf);

    // ---- build CSR (dst-sorted reverse adjacency) ----
    hist_kernel<<<(NE + 255) / 256, 256, 0, stream>>>(dst, deg);
    scan1_kernel<<<SCAN_NB, 256, 0, stream>>>(deg, rowptr, bsum);
    scan2_kernel<<<1, 256, 0, stream>>>(bsum, rowptr);
    scan3_kernel<<<SCAN_NB, 256, 0, stream>>>(rowptr, bsum, cursor);
    fill_kernel<<<(NE + 255) / 256, 256, 0, stream>>>(src, dst, cursor, col);

    // ---- Layers 1+2 fused: gather(x) -> h1 in LDS -> y2, z2 ----
    fconv12_kernel<<<NN / 32, 256, 0, stream>>>(
        (const float4*)x, rowptr, col,
        (const float4*)W1_rel, (const float4*)W1_root, (const float4*)b1,
        (const float4*)W2_rel, (const float4*)W2_root, (const float4*)b2,
        (float4*)bufY, (float4*)bufZ);

    // ---- Layer 3 fused: gather(y2)+relu(z2+agg) + transform 64->32 ----
    fconv3_kernel<<<NN / 32, 256, 0, stream>>>(
        (const float4*)bufY, (const float4*)bufZ, rowptr, col,
        (const float4*)W3_rel, (const float4*)W3_root, (const float4*)b3,
        (float4*)y3, (float4*)z3, NN);

    // ---- Layer 4 fused: gather(y3)+relu(z3+agg) + folded dot -> y4, z4 ----
    fconv4_kernel<<<NN / 32, 256, 0, stream>>>(
        (const float4*)y3, (const float4*)z3, rowptr, col, wf, y4, z4, NN);

    // ---- final gather + pool + FC ----
    gpool_kernel<<<(NN + 255) / 256, 256, 0, stream>>>(
        y4, z4, rowptr, col, batch, sums, counts);
    final_kernel<<<1, 64, 0, stream>>>(sums, counts, bfc, out);
}

// Round 13
// 176.813 us; speedup vs baseline: 1.1945x; 1.0243x over previous
//
#include <hip/hip_runtime.h>

#define NN 40000
#define NE 640000
#define NG 64
#define SCAN_NB ((NN + 255) / 256)   // 157 blocks
#define CCAP 768                     // LDS col-staging chunk (ints)

__device__ __forceinline__ float fcomp(const float4& v, int t) {
    return t == 0 ? v.x : t == 1 ? v.y : t == 2 ? v.z : v.w;
}

// ========== zero scratch (deg+sums+counts) + fold Wfc through layer 4 ==========
__global__ __launch_bounds__(256) void zero_fold_kernel(
        int* __restrict__ p, int n,
        const float* __restrict__ W4rel,
        const float* __restrict__ W4root,
        const float* __restrict__ b4,
        const float* __restrict__ Wfc,
        float* __restrict__ wf) {
    int i = blockIdx.x * 256 + threadIdx.x;
    if (i < n) p[i] = 0;
    if (blockIdx.x == 0) {
        int t = threadIdx.x;
        if (t < 32) {
            float a = 0.f, b = 0.f;
#pragma unroll
            for (int j = 0; j < 16; ++j) {
                float w = Wfc[j];
                a += W4rel[t * 16 + j] * w;
                b += W4root[t * 16 + j] * w;
            }
            wf[t] = a;
            wf[32 + t] = b;
        } else if (t == 32) {
            float s = 0.f;
#pragma unroll
            for (int j = 0; j < 16; ++j) s += b4[j] * Wfc[j];
            wf[64] = s;
        }
    }
}

// ================= CSR build =================
__global__ void hist_kernel(const int* __restrict__ dst, int* __restrict__ deg) {
    int e = blockIdx.x * blockDim.x + threadIdx.x;
    if (e < NE) atomicAdd(&deg[dst[e]], 1);
}

__global__ __launch_bounds__(256) void scan1_kernel(const int* __restrict__ deg,
                                                    int* __restrict__ rowptr,
                                                    int* __restrict__ bsum) {
    __shared__ int ws[4];
    __shared__ int wpre[4];
    int i = blockIdx.x * 256 + threadIdx.x;
    int lane = threadIdx.x & 63, wid = threadIdx.x >> 6;
    int v = (i < NN) ? deg[i] : 0;
    int incl = v;
#pragma unroll
    for (int off = 1; off < 64; off <<= 1) {
        int u = __shfl_up(incl, off, 64);
        if (lane >= off) incl += u;
    }
    if (lane == 63) ws[wid] = incl;
    __syncthreads();
    if (threadIdx.x == 0) {
        int s = 0;
#pragma unroll
        for (int w = 0; w < 4; ++w) { wpre[w] = s; s += ws[w]; }
        bsum[blockIdx.x] = s;
    }
    __syncthreads();
    if (i < NN) rowptr[i] = wpre[wid] + (incl - v);
}

__global__ __launch_bounds__(256) void scan2_kernel(int* __restrict__ bsum,
                                                    int* __restrict__ rowptr) {
    __shared__ int ws[4];
    __shared__ int wpre[4];
    int t = threadIdx.x;
    int lane = t & 63, wid = t >> 6;
    int v = (t < SCAN_NB) ? bsum[t] : 0;
    int incl = v;
#pragma unroll
    for (int off = 1; off < 64; off <<= 1) {
        int u = __shfl_up(incl, off, 64);
        if (lane >= off) incl += u;
    }
    if (lane == 63) ws[wid] = incl;
    __syncthreads();
    if (t == 0) {
        int s = 0;
#pragma unroll
        for (int w = 0; w < 4; ++w) { wpre[w] = s; s += ws[w]; }
        rowptr[NN] = s;
    }
    __syncthreads();
    if (t < SCAN_NB) bsum[t] = wpre[wid] + (incl - v);
}

__global__ __launch_bounds__(256) void scan3_kernel(int* __restrict__ rowptr,
                                                    const int* __restrict__ bsum,
                                                    int* __restrict__ cursor) {
    int i = blockIdx.x * 256 + threadIdx.x;
    if (i < NN) {
        int e = rowptr[i] + bsum[blockIdx.x];
        rowptr[i] = e;
        cursor[i] = e;
    }
}

__global__ void fill_kernel(const int* __restrict__ src, const int* __restrict__ dst,
                            int* __restrict__ cursor, int* __restrict__ col) {
    int e = blockIdx.x * blockDim.x + threadIdx.x;
    if (e < NE) {
        int pos = atomicAdd(&cursor[dst[e]], 1);
        col[pos] = src[e];
    }
}

// ====== fused L1: gather x (LDS col-staged) + conv 32->128 ======
// grid = NN/32 = 1250; LDS = 40.4 KB -> 4 blocks/CU
__global__ __launch_bounds__(256, 4) void fconv1_kernel(
        const float4* __restrict__ x,      // N x 8
        const int* __restrict__ rowptr,
        const int* __restrict__ col,
        const float4* __restrict__ Wrel,   // 32 x 32
        const float4* __restrict__ Wroot,  // 32 x 32
        const float4* __restrict__ bias,   // 32
        float4* __restrict__ out) {        // N x 32
    __shared__ float4 sA[32][9];           // 4.5 KB
    __shared__ float4 sR[32 * 32];         // 16 KB
    __shared__ float4 sT[32 * 32];         // 16 KB
    __shared__ int scol[CCAP];             // 3 KB
    int t = threadIdx.x;
    for (int i = t; i < 32 * 32; i += 256) { sR[i] = Wrel[i]; sT[i] = Wroot[i]; }
    int blk0 = blockIdx.x * 32;
    int ebeg = rowptr[blk0], eend = rowptr[blk0 + 32];
    int na = t >> 3, cA = t & 7;
    int node = blk0 + na;
    int beg = rowptr[node], end = rowptr[node + 1];
    float4 a = {0.f, 0.f, 0.f, 0.f};
    for (int base = ebeg; base < eend; base += CCAP) {
        int cnt = eend - base < CCAP ? eend - base : CCAP;
        __syncthreads();
        for (int i = t; i < cnt; i += 256) scol[i] = col[base + i];
        __syncthreads();
        int lo = beg > base ? beg : base;
        int hi = end < base + cnt ? end : base + cnt;
        int e = lo;
        for (; e + 4 <= hi; e += 4) {
            int i0 = scol[e - base], i1 = scol[e - base + 1];
            int i2 = scol[e - base + 2], i3 = scol[e - base + 3];
            float4 v0 = x[(size_t)i0 * 8 + cA];
            float4 v1 = x[(size_t)i1 * 8 + cA];
            float4 v2 = x[(size_t)i2 * 8 + cA];
            float4 v3 = x[(size_t)i3 * 8 + cA];
            a.x += (v0.x + v1.x) + (v2.x + v3.x);
            a.y += (v0.y + v1.y) + (v2.y + v3.y);
            a.z += (v0.z + v1.z) + (v2.z + v3.z);
            a.w += (v0.w + v1.w) + (v2.w + v3.w);
        }
        for (; e < hi; ++e) {
            float4 v = x[(size_t)scol[e - base] * 8 + cA];
            a.x += v.x; a.y += v.y; a.z += v.z; a.w += v.w;
        }
    }
    sA[na][cA] = a;
    __syncthreads();
    // ---- Phase B: 2 nodes x 8 outputs per thread ----
    int jg = t % 16, mg = t / 16;
    int n0 = blk0 + mg * 2;
    float4 bb0 = bias[2 * jg], bb1 = bias[2 * jg + 1];
    float4 acc00 = bb0, acc01 = bb1, acc10 = bb0, acc11 = bb1;
#pragma unroll 2
    for (int kc = 0; kc < 8; ++kc) {
        float4 a0 = sA[2 * mg][kc];
        float4 a1 = sA[2 * mg + 1][kc];
        float4 x0 = x[(size_t)n0 * 8 + kc];
        float4 x1 = x[(size_t)(n0 + 1) * 8 + kc];
#pragma unroll
        for (int tt = 0; tt < 4; ++tt) {
            int k = kc * 4 + tt;
            float4 wr0 = sR[k * 32 + 2 * jg], wr1 = sR[k * 32 + 2 * jg + 1];
            float4 wt0 = sT[k * 32 + 2 * jg], wt1 = sT[k * 32 + 2 * jg + 1];
            float av0 = fcomp(a0, tt), xv0 = fcomp(x0, tt);
            float av1 = fcomp(a1, tt), xv1 = fcomp(x1, tt);
            acc00.x += av0 * wr0.x + xv0 * wt0.x;
            acc00.y += av0 * wr0.y + xv0 * wt0.y;
            acc00.z += av0 * wr0.z + xv0 * wt0.z;
            acc00.w += av0 * wr0.w + xv0 * wt0.w;
            acc01.x += av0 * wr1.x + xv0 * wt1.x;
            acc01.y += av0 * wr1.y + xv0 * wt1.y;
            acc01.z += av0 * wr1.z + xv0 * wt1.z;
            acc01.w += av0 * wr1.w + xv0 * wt1.w;
            acc10.x += av1 * wr0.x + xv1 * wt0.x;
            acc10.y += av1 * wr0.y + xv1 * wt0.y;
            acc10.z += av1 * wr0.z + xv1 * wt0.z;
            acc10.w += av1 * wr0.w + xv1 * wt0.w;
            acc11.x += av1 * wr1.x + xv1 * wt1.x;
            acc11.y += av1 * wr1.y + xv1 * wt1.y;
            acc11.z += av1 * wr1.z + xv1 * wt1.z;
            acc11.w += av1 * wr1.w + xv1 * wt1.w;
        }
    }
    float4 r;
    r.x = fmaxf(acc00.x, 0.f); r.y = fmaxf(acc00.y, 0.f);
    r.z = fmaxf(acc00.z, 0.f); r.w = fmaxf(acc00.w, 0.f);
    out[(size_t)n0 * 32 + 2 * jg] = r;
    r.x = fmaxf(acc01.x, 0.f); r.y = fmaxf(acc01.y, 0.f);
    r.z = fmaxf(acc01.z, 0.f); r.w = fmaxf(acc01.w, 0.f);
    out[(size_t)n0 * 32 + 2 * jg + 1] = r;
    r.x = fmaxf(acc10.x, 0.f); r.y = fmaxf(acc10.y, 0.f);
    r.z = fmaxf(acc10.z, 0.f); r.w = fmaxf(acc10.w, 0.f);
    out[(size_t)(n0 + 1) * 32 + 2 * jg] = r;
    r.x = fmaxf(acc11.x, 0.f); r.y = fmaxf(acc11.y, 0.f);
    r.z = fmaxf(acc11.z, 0.f); r.w = fmaxf(acc11.w, 0.f);
    out[(size_t)(n0 + 1) * 32 + 2 * jg + 1] = r;
}

// ====== L2 transform: y = h@Wrel, z = h@Wroot + b (128->64) ======
template<int K, int DOUT, int NPT>
__global__ __launch_bounds__(256, 6) void mmyz_kernel(
        const float4* __restrict__ h,
        const float4* __restrict__ Wrel,
        const float4* __restrict__ Wroot,
        const float4* __restrict__ bias,
        float4* __restrict__ y,
        float4* __restrict__ z, int n) {
    constexpr int JL = DOUT / 4, MG = 256 / JL, NPB = MG * NPT;
    constexpr int SLAB = (K * JL * 2 * 16 <= 16384) ? K : 32;
    constexpr int NS = K / SLAB;
    __shared__ float4 sR[SLAB * JL];
    __shared__ float4 sT[SLAB * JL];
    int jl = threadIdx.x % JL;
    int mg = threadIdx.x / JL;
    int node0 = blockIdx.x * NPB + mg * NPT;
    int nm[NPT]; bool ok[NPT];
#pragma unroll
    for (int m = 0; m < NPT; ++m) {
        int nd = node0 + m; ok[m] = nd < n; nm[m] = ok[m] ? nd : 0;
    }
    float4 bb = bias[jl];
    float4 ay[NPT], az[NPT];
#pragma unroll
    for (int m = 0; m < NPT; ++m) {
        ay[m].x = 0.f; ay[m].y = 0.f; ay[m].z = 0.f; ay[m].w = 0.f;
        az[m] = bb;
    }
    for (int s = 0; s < NS; ++s) {
        if (NS > 1) __syncthreads();
        for (int i = threadIdx.x; i < SLAB * JL; i += 256) {
            sR[i] = Wrel[s * SLAB * JL + i];
            sT[i] = Wroot[s * SLAB * JL + i];
        }
        __syncthreads();
#pragma unroll 2
        for (int kc = 0; kc < SLAB / 4; ++kc) {
            float4 h4[NPT];
#pragma unroll
            for (int m = 0; m < NPT; ++m)
                h4[m] = h[(size_t)nm[m] * (K / 4) + s * (SLAB / 4) + kc];
#pragma unroll
            for (int tt = 0; tt < 4; ++tt) {
                float4 wr = sR[(kc * 4 + tt) * JL + jl];
                float4 wt = sT[(kc * 4 + tt) * JL + jl];
#pragma unroll
                for (int m = 0; m < NPT; ++m) {
                    float hv = fcomp(h4[m], tt);
                    ay[m].x += hv * wr.x; ay[m].y += hv * wr.y;
                    ay[m].z += hv * wr.z; ay[m].w += hv * wr.w;
                    az[m].x += hv * wt.x; az[m].y += hv * wt.y;
                    az[m].z += hv * wt.z; az[m].w += hv * wt.w;
                }
            }
        }
    }
#pragma unroll
    for (int m = 0; m < NPT; ++m) {
        if (!ok[m]) continue;
        y[(size_t)nm[m] * JL + jl] = ay[m];
        z[(size_t)nm[m] * JL + jl] = az[m];
    }
}

// ====== fused L3: gather y2 (LDS col-staged) + relu + transform 64->32 ======
// grid = NN/32 = 1250; LDS = 27.5 KB -> 5 blocks/CU
__global__ __launch_bounds__(256, 5) void fconv3_kernel(
        const float4* __restrict__ y,      // y2: N x 16
        const float4* __restrict__ z,      // z2: N x 16
        const int* __restrict__ rowptr,
        const int* __restrict__ col,
        const float4* __restrict__ Wrel,   // 64 x 8
        const float4* __restrict__ Wroot,  // 64 x 8
        const float4* __restrict__ bias,   // 8
        float4* __restrict__ y3,
        float4* __restrict__ z3) {
    __shared__ float4 sH[32][17];          // 8.5 KB
    __shared__ float4 sR[64 * 8];          // 8 KB
    __shared__ float4 sT[64 * 8];          // 8 KB
    __shared__ int scol[CCAP];             // 3 KB
    int t = threadIdx.x;
    for (int i = t; i < 64 * 8; i += 256) { sR[i] = Wrel[i]; sT[i] = Wroot[i]; }
    int blk0 = blockIdx.x * 32;
    int ebeg = rowptr[blk0], eend = rowptr[blk0 + 32];
    // two gather tasks per thread: nodes na0 and na0+16, same col c
    int na0 = t >> 4, c = t & 15;
    int node0 = blk0 + na0, node1 = node0 + 16;
    int beg0 = rowptr[node0], end0 = rowptr[node0 + 1];
    int beg1 = rowptr[node1], end1 = rowptr[node1 + 1];
    float4 a0 = z[(size_t)node0 * 16 + c];
    float4 a1 = z[(size_t)node1 * 16 + c];
    for (int base = ebeg; base < eend; base += CCAP) {
        int cnt = eend - base < CCAP ? eend - base : CCAP;
        __syncthreads();
        for (int i = t; i < cnt; i += 256) scol[i] = col[base + i];
        __syncthreads();
        int lo = beg0 > base ? beg0 : base;
        int hi = end0 < base + cnt ? end0 : base + cnt;
        int e = lo;
        for (; e + 4 <= hi; e += 4) {
            int i0 = scol[e - base], i1 = scol[e - base + 1];
            int i2 = scol[e - base + 2], i3 = scol[e - base + 3];
            float4 v0 = y[(size_t)i0 * 16 + c];
            float4 v1 = y[(size_t)i1 * 16 + c];
            float4 v2 = y[(size_t)i2 * 16 + c];
            float4 v3 = y[(size_t)i3 * 16 + c];
            a0.x += (v0.x + v1.x) + (v2.x + v3.x);
            a0.y += (v0.y + v1.y) + (v2.y + v3.y);
            a0.z += (v0.z + v1.z) + (v2.z + v3.z);
            a0.w += (v0.w + v1.w) + (v2.w + v3.w);
        }
        for (; e < hi; ++e) {
            float4 v = y[(size_t)scol[e - base] * 16 + c];
            a0.x += v.x; a0.y += v.y; a0.z += v.z; a0.w += v.w;
        }
        lo = beg1 > base ? beg1 : base;
        hi = end1 < base + cnt ? end1 : base + cnt;
        e = lo;
        for (; e + 4 <= hi; e += 4) {
            int i0 = scol[e - base], i1 = scol[e - base + 1];
            int i2 = scol[e - base + 2], i3 = scol[e - base + 3];
            float4 v0 = y[(size_t)i0 * 16 + c];
            float4 v1 = y[(size_t)i1 * 16 + c];
            float4 v2 = y[(size_t)i2 * 16 + c];
            float4 v3 = y[(size_t)i3 * 16 + c];
            a1.x += (v0.x + v1.x) + (v2.x + v3.x);
            a1.y += (v0.y + v1.y) + (v2.y + v3.y);
            a1.z += (v0.z + v1.z) + (v2.z + v3.z);
            a1.w += (v0.w + v1.w) + (v2.w + v3.w);
        }
        for (; e < hi; ++e) {
            float4 v = y[(size_t)scol[e - base] * 16 + c];
            a1.x += v.x; a1.y += v.y; a1.z += v.z; a1.w += v.w;
        }
    }
    a0.x = fmaxf(a0.x, 0.f); a0.y = fmaxf(a0.y, 0.f);
    a0.z = fmaxf(a0.z, 0.f); a0.w = fmaxf(a0.w, 0.f);
    a1.x = fmaxf(a1.x, 0.f); a1.y = fmaxf(a1.y, 0.f);
    a1.z = fmaxf(a1.z, 0.f); a1.w = fmaxf(a1.w, 0.f);
    sH[na0][c] = a0;
    sH[na0 + 16][c] = a1;
    __syncthreads();
    // ---- Phase B: 1 node x 4 outputs per thread ----
    int jl = t & 7, mg = t >> 3;
    int node = blk0 + mg;
    float4 ay = {0.f, 0.f, 0.f, 0.f};
    float4 az = bias[jl];
#pragma unroll 4
    for (int kc = 0; kc < 16; ++kc) {
        float4 h4 = sH[mg][kc];
#pragma unroll
        for (int tt = 0; tt < 4; ++tt) {
            float hv = fcomp(h4, tt);
            float4 wr = sR[(kc * 4 + tt) * 8 + jl];
            float4 wt = sT[(kc * 4 + tt) * 8 + jl];
            ay.x += hv * wr.x; ay.y += hv * wr.y;
            ay.z += hv * wr.z; ay.w += hv * wr.w;
            az.x += hv * wt.x; az.y += hv * wt.y;
            az.z += hv * wt.z; az.w += hv * wt.w;
        }
    }
    y3[(size_t)node * 8 + jl] = ay;
    z3[(size_t)node * 8 + jl] = az;
}

// ====== fused L4: gather y3 (LDS col-staged) + relu + folded dot -> y4, z4 ======
// grid = NN/32 = 1250; LDS ~8 KB -> 8 blocks/CU
__global__ __launch_bounds__(256, 8) void fconv4_kernel(
        const float4* __restrict__ y,      // y3: N x 8
        const float4* __restrict__ z,      // z3: N x 8
        const int* __restrict__ rowptr,
        const int* __restrict__ col,
        const float* __restrict__ wf,      // 65
        float* __restrict__ y4,
        float* __restrict__ z4) {
    __shared__ float4 sH[32][9];
    __shared__ float4 sF[8], sRF[8];
    __shared__ float sB;
    __shared__ int scol[CCAP];
    int t = threadIdx.x;
    if (t < 8) sF[t] = ((const float4*)wf)[t];
    else if (t < 16) sRF[t - 8] = ((const float4*)wf)[t];
    else if (t == 16) sB = wf[64];
    int blk0 = blockIdx.x * 32;
    int ebeg = rowptr[blk0], eend = rowptr[blk0 + 32];
    int na = t >> 3, c = t & 7;
    int node = blk0 + na;
    int beg = rowptr[node], end = rowptr[node + 1];
    float4 a = z[(size_t)node * 8 + c];
    for (int base = ebeg; base < eend; base += CCAP) {
        int cnt = eend - base < CCAP ? eend - base : CCAP;
        __syncthreads();
        for (int i = t; i < cnt; i += 256) scol[i] = col[base + i];
        __syncthreads();
        int lo = beg > base ? beg : base;
        int hi = end < base + cnt ? end : base + cnt;
        int e = lo;
        for (; e + 4 <= hi; e += 4) {
            int i0 = scol[e - base], i1 = scol[e - base + 1];
            int i2 = scol[e - base + 2], i3 = scol[e - base + 3];
            float4 v0 = y[(size_t)i0 * 8 + c];
            float4 v1 = y[(size_t)i1 * 8 + c];
            float4 v2 = y[(size_t)i2 * 8 + c];
            float4 v3 = y[(size_t)i3 * 8 + c];
            a.x += (v0.x + v1.x) + (v2.x + v3.x);
            a.y += (v0.y + v1.y) + (v2.y + v3.y);
            a.z += (v0.z + v1.z) + (v2.z + v3.z);
            a.w += (v0.w + v1.w) + (v2.w + v3.w);
        }
        for (; e < hi; ++e) {
            float4 v = y[(size_t)scol[e - base] * 8 + c];
            a.x += v.x; a.y += v.y; a.z += v.z; a.w += v.w;
        }
    }
    a.x = fmaxf(a.x, 0.f); a.y = fmaxf(a.y, 0.f);
    a.z = fmaxf(a.z, 0.f); a.w = fmaxf(a.w, 0.f);
    sH[na][c] = a;
    __syncthreads();
    if (t < 32) {
        int nd = blk0 + t;
        float ay = 0.f, az = 0.f;
#pragma unroll
        for (int kc = 0; kc < 8; ++kc) {
            float4 h4 = sH[t][kc];
            float4 f = sF[kc], r = sRF[kc];
            ay += h4.x * f.x + h4.y * f.y + h4.z * f.z + h4.w * f.w;
            az += h4.x * r.x + h4.y * r.y + h4.z * r.z + h4.w * r.w;
        }
        y4[nd] = ay;
        z4[nd] = az + sB;
    }
}

// ====== scalar gather + pool: thread-per-node, per-block LDS graph bins ======
__global__ __launch_bounds__(256) void gpool_kernel(
        const float* __restrict__ y4,
        const float* __restrict__ z4,
        const int* __restrict__ rowptr,
        const int* __restrict__ col,
        const int* __restrict__ batch,
        float* __restrict__ sums,
        float* __restrict__ counts) {
    __shared__ float ls[NG];
    __shared__ float lc[NG];
    if (threadIdx.x < NG) { ls[threadIdx.x] = 0.f; lc[threadIdx.x] = 0.f; }
    __syncthreads();
    int nd = blockIdx.x * 256 + threadIdx.x;
    if (nd < NN) {
        float v = z4[nd];
        int beg = rowptr[nd], end = rowptr[nd + 1];
        int e = beg;
        for (; e + 4 <= end; e += 4) {
            v += (y4[col[e]] + y4[col[e + 1]]) + (y4[col[e + 2]] + y4[col[e + 3]]);
        }
        for (; e < end; ++e) v += y4[col[e]];
        int g = batch[nd];
        atomicAdd(&ls[g], v);
        atomicAdd(&lc[g], 1.f);
    }
    __syncthreads();
    if (threadIdx.x < NG && lc[threadIdx.x] > 0.f) {
        atomicAdd(&sums[threadIdx.x], ls[threadIdx.x]);
        atomicAdd(&counts[threadIdx.x], lc[threadIdx.x]);
    }
}

// ================= finalize =================
__global__ void final_kernel(const float* __restrict__ sums,
                             const float* __restrict__ counts,
                             const float* __restrict__ bfc,
                             float* __restrict__ out) {
    int g = threadIdx.x;
    if (g >= NG) return;
    float c = fmaxf(counts[g], 1.0f);
    out[g] = sums[g] / c + bfc[0];
}

extern "C" void kernel_launch(void* const* d_in, const int* in_sizes, int n_in,
                              void* d_out, int out_size, void* d_ws, size_t ws_size,
                              hipStream_t stream) {
    const float* x       = (const float*)d_in[0];
    const int*   ei      = (const int*)d_in[1];
    const int*   batch   = (const int*)d_in[2];
    const float* W1_rel  = (const float*)d_in[3];
    const float* b1      = (const float*)d_in[4];
    const float* W1_root = (const float*)d_in[5];
    const float* W2_rel  = (const float*)d_in[6];
    const float* b2      = (const float*)d_in[7];
    const float* W2_root = (const float*)d_in[8];
    const float* W3_rel  = (const float*)d_in[9];
    const float* b3      = (const float*)d_in[10];
    const float* W3_root = (const float*)d_in[11];
    const float* W4_rel  = (const float*)d_in[12];
    const float* b4      = (const float*)d_in[13];
    const float* W4_root = (const float*)d_in[14];
    const float* Wfc     = (const float*)d_in[15];
    const float* bfc     = (const float*)d_in[16];
    float* out = (float*)d_out;

    const int* src = ei;        // edge_index[0]
    const int* dst = ei + NE;   // edge_index[1]

    // workspace layout
    float* bufH   = (float*)d_ws;                    // N x 128  (h1)
    float* bufY   = bufH + (size_t)NN * 128;         // N x 64   (y2)
    float* bufZ   = bufY + (size_t)NN * 64;          // N x 64   (z2)
    float* y3     = bufZ + (size_t)NN * 64;          // N x 32
    float* z3     = y3 + (size_t)NN * 32;            // N x 32
    float* y4     = z3 + (size_t)NN * 32;            // N
    float* z4     = y4 + NN;                         // N
    float* wf     = z4 + NN;                         // 65 (pad 68)
    int*   deg    = (int*)(wf + 68);                 // N      -- zeroed block start
    float* sums   = (float*)(deg + NN);              // G
    float* counts = sums + NG;                       // G      -- zeroed block end
    int*   rowptr = (int*)(counts + NG);             // N+1
    int*   cursor = rowptr + NN + 1;                 // N
    int*   col    = cursor + NN;                     // E
    int*   bsum   = col + NE;                        // SCAN_NB

    // ---- zero deg+sums+counts AND fold Wfc (one launch) ----
    zero_fold_kernel<<<(NN + 2 * NG + 255) / 256, 256, 0, stream>>>(
        deg, NN + 2 * NG, W4_rel, W4_root, b4, Wfc, wf);

    // ---- build CSR (dst-sorted reverse adjacency) ----
    hist_kernel<<<(NE + 255) / 256, 256, 0, stream>>>(dst, deg);
    scan1_kernel<<<SCAN_NB, 256, 0, stream>>>(deg, rowptr, bsum);
    scan2_kernel<<<1, 256, 0, stream>>>(bsum, rowptr);
    scan3_kernel<<<SCAN_NB, 256, 0, stream>>>(rowptr, bsum, cursor);
    fill_kernel<<<(NE + 255) / 256, 256, 0, stream>>>(src, dst, cursor, col);

    // ---- Layer 1 fused: gather(x) + conv 32->128 ----
    fconv1_kernel<<<NN / 32, 256, 0, stream>>>(
        (const float4*)x, rowptr, col,
        (const float4*)W1_rel, (const float4*)W1_root, (const float4*)b1,
        (float4*)bufH);

    // ---- Layer 2 transform: h1 -> y2, z2 (128 -> 64) ----
    mmyz_kernel<128, 64, 2><<<(NN + 31) / 32, 256, 0, stream>>>(
        (const float4*)bufH, (const float4*)W2_rel, (const float4*)W2_root,
        (const float4*)b2, (float4*)bufY, (float4*)bufZ, NN);

    // ---- Layer 3 fused: gather(y2)+relu(z2+agg) + transform 64->32 ----
    fconv3_kernel<<<NN / 32, 256, 0, stream>>>(
        (const float4*)bufY, (const float4*)bufZ, rowptr, col,
        (const float4*)W3_rel, (const float4*)W3_root, (const float4*)b3,
        (float4*)y3, (float4*)z3);

    // ---- Layer 4 fused: gather(y3)+relu(z3+agg) + folded dot -> y4, z4 ----
    fconv4_kernel<<<NN / 32, 256, 0, stream>>>(
        (const float4*)y3, (const float4*)z3, rowptr, col, wf, y4, z4);

    // ---- final gather + pool + FC ----
    gpool_kernel<<<(NN + 255) / 256, 256, 0, stream>>>(
        y4, z4, rowptr, col, batch, sums, counts);
    final_kernel<<<1, 64, 0, stream>>>(sums, counts, bfc, out);
}

// Round 14
// 155.433 us; speedup vs baseline: 1.3588x; 1.1376x over previous
//
#include <hip/hip_runtime.h>

#define NN 40000
#define NE 640000
#define NG 64
#define SCAN_NB ((NN + 255) / 256)   // 157 blocks
#define CCAP 768                     // LDS col-staging chunk (ints)

__device__ __forceinline__ float fcomp(const float4& v, int t) {
    return t == 0 ? v.x : t == 1 ? v.y : t == 2 ? v.z : v.w;
}
// ---- bf16 pack/unpack (RNE) ----
__device__ __forceinline__ unsigned int pack2bf(float a, float b) {
    unsigned int ua = __float_as_uint(a);
    unsigned int ub = __float_as_uint(b);
    ua = (ua + 0x7fffu + ((ua >> 16) & 1u)) >> 16;
    ub = (ub + 0x7fffu + ((ub >> 16) & 1u)) >> 16;
    return ua | (ub << 16);
}
__device__ __forceinline__ uint2 pack4bf(const float4& v) {
    return make_uint2(pack2bf(v.x, v.y), pack2bf(v.z, v.w));
}
__device__ __forceinline__ float lo2f(unsigned int u) { return __uint_as_float(u << 16); }
__device__ __forceinline__ float hi2f(unsigned int u) { return __uint_as_float(u & 0xffff0000u); }

// ===== prep: zero deg+sums+counts+ctr, convert x -> bf16, fold Wfc into L4 =====
// grid = 1250 (NN*8/256 exactly)
__global__ __launch_bounds__(256) void prep_kernel(
        int* __restrict__ zp, int nz,
        const float4* __restrict__ x4,     // NN*8 float4
        uint2* __restrict__ xb,            // NN*8 uint2
        const float* __restrict__ W4rel,
        const float* __restrict__ W4root,
        const float* __restrict__ b4,
        const float* __restrict__ Wfc,
        float* __restrict__ wf) {
    int i = blockIdx.x * 256 + threadIdx.x;
    if (i < nz) zp[i] = 0;
    if (i < NN * 8) { float4 v = x4[i]; xb[i] = pack4bf(v); }
    if (blockIdx.x == 0) {
        int t = threadIdx.x;
        if (t < 32) {
            float a = 0.f, b = 0.f;
#pragma unroll
            for (int j = 0; j < 16; ++j) {
                float w = Wfc[j];
                a += W4rel[t * 16 + j] * w;
                b += W4root[t * 16 + j] * w;
            }
            wf[t] = a;
            wf[32 + t] = b;
        } else if (t == 32) {
            float s = 0.f;
#pragma unroll
            for (int j = 0; j < 16; ++j) s += b4[j] * Wfc[j];
            wf[64] = s;
        }
    }
}

// ================= CSR build =================
__global__ void hist_kernel(const int* __restrict__ dst, int* __restrict__ deg,
                            int* __restrict__ epos) {
    int e = blockIdx.x * blockDim.x + threadIdx.x;
    if (e < NE) epos[e] = atomicAdd(&deg[dst[e]], 1);
}

__global__ __launch_bounds__(256) void scan1_kernel(const int* __restrict__ deg,
                                                    int* __restrict__ rowptr,
                                                    int* __restrict__ bsum) {
    __shared__ int ws[4];
    __shared__ int wpre[4];
    int i = blockIdx.x * 256 + threadIdx.x;
    int lane = threadIdx.x & 63, wid = threadIdx.x >> 6;
    int v = (i < NN) ? deg[i] : 0;
    int incl = v;
#pragma unroll
    for (int off = 1; off < 64; off <<= 1) {
        int u = __shfl_up(incl, off, 64);
        if (lane >= off) incl += u;
    }
    if (lane == 63) ws[wid] = incl;
    __syncthreads();
    if (threadIdx.x == 0) {
        int s = 0;
#pragma unroll
        for (int w = 0; w < 4; ++w) { wpre[w] = s; s += ws[w]; }
        bsum[blockIdx.x] = s;
    }
    __syncthreads();
    if (i < NN) rowptr[i] = wpre[wid] + (incl - v);
}

// merged scan2+scan3: each block reduces sum(bsum[0..b-1]) and adds to its slice
__global__ __launch_bounds__(256) void scan23_kernel(int* __restrict__ rowptr,
                                                     const int* __restrict__ bsum) {
    __shared__ int ws[4];
    int t = threadIdx.x, b = blockIdx.x;
    int v = (t < b) ? bsum[t] : 0;           // b <= 156 < 256
#pragma unroll
    for (int off = 32; off; off >>= 1) v += __shfl_xor(v, off, 64);
    if ((t & 63) == 0) ws[t >> 6] = v;
    __syncthreads();
    int soff = ws[0] + ws[1] + ws[2] + ws[3];
    int i = b * 256 + t;
    if (i < NN) rowptr[i] += soff;
    if (b == SCAN_NB - 1 && t == 0) rowptr[NN] = soff + bsum[b];
}

__global__ void fill_kernel(const int* __restrict__ src, const int* __restrict__ dst,
                            const int* __restrict__ rowptr, const int* __restrict__ epos,
                            int* __restrict__ col) {
    int e = blockIdx.x * blockDim.x + threadIdx.x;
    if (e < NE) col[rowptr[dst[e]] + epos[e]] = src[e];
}

// ====== fused L1: gather xb (bf16) + conv 32->128 ======
// grid = NN/32 = 1250; LDS ~40 KB -> 4 blocks/CU
__global__ __launch_bounds__(256, 4) void fconv1_kernel(
        const uint2* __restrict__ xb,      // N x 8 (bf16x4)
        const float4* __restrict__ x,      // N x 8 (fp32, root term)
        const int* __restrict__ rowptr,
        const int* __restrict__ col,
        const float4* __restrict__ Wrel,   // 32 x 32
        const float4* __restrict__ Wroot,  // 32 x 32
        const float4* __restrict__ bias,   // 32
        float4* __restrict__ out) {        // N x 32
    __shared__ float4 sA[32][9];
    __shared__ float4 sR[32 * 32];
    __shared__ float4 sT[32 * 32];
    __shared__ int scol[CCAP];
    int t = threadIdx.x;
    for (int i = t; i < 32 * 32; i += 256) { sR[i] = Wrel[i]; sT[i] = Wroot[i]; }
    int blk0 = blockIdx.x * 32;
    int ebeg = rowptr[blk0], eend = rowptr[blk0 + 32];
    int na = t >> 3, cA = t & 7;
    int node = blk0 + na;
    int beg = rowptr[node], end = rowptr[node + 1];
    float4 a = {0.f, 0.f, 0.f, 0.f};
    for (int base = ebeg; base < eend; base += CCAP) {
        int cnt = eend - base < CCAP ? eend - base : CCAP;
        __syncthreads();
        for (int i = t; i < cnt; i += 256) scol[i] = col[base + i];
        __syncthreads();
        int lo = beg > base ? beg : base;
        int hi = end < base + cnt ? end : base + cnt;
        int e = lo;
        for (; e + 4 <= hi; e += 4) {
            int i0 = scol[e - base], i1 = scol[e - base + 1];
            int i2 = scol[e - base + 2], i3 = scol[e - base + 3];
            uint2 u0 = xb[(size_t)i0 * 8 + cA];
            uint2 u1 = xb[(size_t)i1 * 8 + cA];
            uint2 u2 = xb[(size_t)i2 * 8 + cA];
            uint2 u3 = xb[(size_t)i3 * 8 + cA];
            a.x += (lo2f(u0.x) + lo2f(u1.x)) + (lo2f(u2.x) + lo2f(u3.x));
            a.y += (hi2f(u0.x) + hi2f(u1.x)) + (hi2f(u2.x) + hi2f(u3.x));
            a.z += (lo2f(u0.y) + lo2f(u1.y)) + (lo2f(u2.y) + lo2f(u3.y));
            a.w += (hi2f(u0.y) + hi2f(u1.y)) + (hi2f(u2.y) + hi2f(u3.y));
        }
        for (; e < hi; ++e) {
            uint2 u = xb[(size_t)scol[e - base] * 8 + cA];
            a.x += lo2f(u.x); a.y += hi2f(u.x); a.z += lo2f(u.y); a.w += hi2f(u.y);
        }
    }
    sA[na][cA] = a;
    __syncthreads();
    // ---- Phase B: 2 nodes x 8 outputs per thread (root term in fp32) ----
    int jg = t % 16, mg = t / 16;
    int n0 = blk0 + mg * 2;
    float4 bb0 = bias[2 * jg], bb1 = bias[2 * jg + 1];
    float4 acc00 = bb0, acc01 = bb1, acc10 = bb0, acc11 = bb1;
#pragma unroll 2
    for (int kc = 0; kc < 8; ++kc) {
        float4 a0 = sA[2 * mg][kc];
        float4 a1 = sA[2 * mg + 1][kc];
        float4 x0 = x[(size_t)n0 * 8 + kc];
        float4 x1 = x[(size_t)(n0 + 1) * 8 + kc];
#pragma unroll
        for (int tt = 0; tt < 4; ++tt) {
            int k = kc * 4 + tt;
            float4 wr0 = sR[k * 32 + 2 * jg], wr1 = sR[k * 32 + 2 * jg + 1];
            float4 wt0 = sT[k * 32 + 2 * jg], wt1 = sT[k * 32 + 2 * jg + 1];
            float av0 = fcomp(a0, tt), xv0 = fcomp(x0, tt);
            float av1 = fcomp(a1, tt), xv1 = fcomp(x1, tt);
            acc00.x += av0 * wr0.x + xv0 * wt0.x;
            acc00.y += av0 * wr0.y + xv0 * wt0.y;
            acc00.z += av0 * wr0.z + xv0 * wt0.z;
            acc00.w += av0 * wr0.w + xv0 * wt0.w;
            acc01.x += av0 * wr1.x + xv0 * wt1.x;
            acc01.y += av0 * wr1.y + xv0 * wt1.y;
            acc01.z += av0 * wr1.z + xv0 * wt1.z;
            acc01.w += av0 * wr1.w + xv0 * wt1.w;
            acc10.x += av1 * wr0.x + xv1 * wt0.x;
            acc10.y += av1 * wr0.y + xv1 * wt0.y;
            acc10.z += av1 * wr0.z + xv1 * wt0.z;
            acc10.w += av1 * wr0.w + xv1 * wt0.w;
            acc11.x += av1 * wr1.x + xv1 * wt1.x;
            acc11.y += av1 * wr1.y + xv1 * wt1.y;
            acc11.z += av1 * wr1.z + xv1 * wt1.z;
            acc11.w += av1 * wr1.w + xv1 * wt1.w;
        }
    }
    float4 r;
    r.x = fmaxf(acc00.x, 0.f); r.y = fmaxf(acc00.y, 0.f);
    r.z = fmaxf(acc00.z, 0.f); r.w = fmaxf(acc00.w, 0.f);
    out[(size_t)n0 * 32 + 2 * jg] = r;
    r.x = fmaxf(acc01.x, 0.f); r.y = fmaxf(acc01.y, 0.f);
    r.z = fmaxf(acc01.z, 0.f); r.w = fmaxf(acc01.w, 0.f);
    out[(size_t)n0 * 32 + 2 * jg + 1] = r;
    r.x = fmaxf(acc10.x, 0.f); r.y = fmaxf(acc10.y, 0.f);
    r.z = fmaxf(acc10.z, 0.f); r.w = fmaxf(acc10.w, 0.f);
    out[(size_t)(n0 + 1) * 32 + 2 * jg] = r;
    r.x = fmaxf(acc11.x, 0.f); r.y = fmaxf(acc11.y, 0.f);
    r.z = fmaxf(acc11.z, 0.f); r.w = fmaxf(acc11.w, 0.f);
    out[(size_t)(n0 + 1) * 32 + 2 * jg + 1] = r;
}

// ====== L2 transform: y2(bf16) = h1@W2rel, z2(fp32) = h1@W2root + b2 ======
// grid = NN/32 = 1250
__global__ __launch_bounds__(256, 6) void mmyz_kernel(
        const float4* __restrict__ h,      // N x 32
        const float4* __restrict__ Wrel,   // 128 x 16
        const float4* __restrict__ Wroot,  // 128 x 16
        const float4* __restrict__ bias,   // 16
        uint2* __restrict__ y2b,           // N x 16 (bf16x4)
        float4* __restrict__ z2) {
    __shared__ float4 sR[32 * 16];
    __shared__ float4 sT[32 * 16];
    int jl = threadIdx.x % 16;
    int mg = threadIdx.x / 16;
    int n0 = blockIdx.x * 32 + mg * 2;
    float4 bb = bias[jl];
    float4 ay0 = {0.f, 0.f, 0.f, 0.f}, ay1 = {0.f, 0.f, 0.f, 0.f};
    float4 az0 = bb, az1 = bb;
    for (int s = 0; s < 4; ++s) {
        if (s) __syncthreads();
        for (int i = threadIdx.x; i < 512; i += 256) {
            sR[i] = Wrel[s * 512 + i];
            sT[i] = Wroot[s * 512 + i];
        }
        __syncthreads();
#pragma unroll 2
        for (int kc = 0; kc < 8; ++kc) {
            float4 h0 = h[(size_t)n0 * 32 + s * 8 + kc];
            float4 h1 = h[(size_t)(n0 + 1) * 32 + s * 8 + kc];
#pragma unroll
            for (int tt = 0; tt < 4; ++tt) {
                float4 wr = sR[(kc * 4 + tt) * 16 + jl];
                float4 wt = sT[(kc * 4 + tt) * 16 + jl];
                float v0 = fcomp(h0, tt), v1 = fcomp(h1, tt);
                ay0.x += v0 * wr.x; ay0.y += v0 * wr.y;
                ay0.z += v0 * wr.z; ay0.w += v0 * wr.w;
                az0.x += v0 * wt.x; az0.y += v0 * wt.y;
                az0.z += v0 * wt.z; az0.w += v0 * wt.w;
                ay1.x += v1 * wr.x; ay1.y += v1 * wr.y;
                ay1.z += v1 * wr.z; ay1.w += v1 * wr.w;
                az1.x += v1 * wt.x; az1.y += v1 * wt.y;
                az1.z += v1 * wt.z; az1.w += v1 * wt.w;
            }
        }
    }
    y2b[(size_t)n0 * 16 + jl] = pack4bf(ay0);
    z2[(size_t)n0 * 16 + jl] = az0;
    y2b[(size_t)(n0 + 1) * 16 + jl] = pack4bf(ay1);
    z2[(size_t)(n0 + 1) * 16 + jl] = az1;
}

// ====== fused L3: gather y2(bf16) + relu(z2+agg) + transform 64->32 ======
// grid = NN/32 = 1250; LDS ~28 KB -> 5 blocks/CU
__global__ __launch_bounds__(256, 5) void fconv3_kernel(
        const uint2* __restrict__ yb,      // y2: N x 16 (bf16x4)
        const float4* __restrict__ z,      // z2: N x 16
        const int* __restrict__ rowptr,
        const int* __restrict__ col,
        const float4* __restrict__ Wrel,   // 64 x 8
        const float4* __restrict__ Wroot,  // 64 x 8
        const float4* __restrict__ bias,   // 8
        uint2* __restrict__ y3b,           // N x 8 (bf16x4)
        float4* __restrict__ z3) {
    __shared__ float4 sH[32][17];
    __shared__ float4 sR[64 * 8];
    __shared__ float4 sT[64 * 8];
    __shared__ int scol[CCAP];
    int t = threadIdx.x;
    for (int i = t; i < 64 * 8; i += 256) { sR[i] = Wrel[i]; sT[i] = Wroot[i]; }
    int blk0 = blockIdx.x * 32;
    int ebeg = rowptr[blk0], eend = rowptr[blk0 + 32];
    int na0 = t >> 4, c = t & 15;
    int node0 = blk0 + na0, node1 = node0 + 16;
    int beg0 = rowptr[node0], end0 = rowptr[node0 + 1];
    int beg1 = rowptr[node1], end1 = rowptr[node1 + 1];
    float4 a0 = z[(size_t)node0 * 16 + c];
    float4 a1 = z[(size_t)node1 * 16 + c];
    for (int base = ebeg; base < eend; base += CCAP) {
        int cnt = eend - base < CCAP ? eend - base : CCAP;
        __syncthreads();
        for (int i = t; i < cnt; i += 256) scol[i] = col[base + i];
        __syncthreads();
        int lo = beg0 > base ? beg0 : base;
        int hi = end0 < base + cnt ? end0 : base + cnt;
        int e = lo;
        for (; e + 4 <= hi; e += 4) {
            int i0 = scol[e - base], i1 = scol[e - base + 1];
            int i2 = scol[e - base + 2], i3 = scol[e - base + 3];
            uint2 u0 = yb[(size_t)i0 * 16 + c];
            uint2 u1 = yb[(size_t)i1 * 16 + c];
            uint2 u2 = yb[(size_t)i2 * 16 + c];
            uint2 u3 = yb[(size_t)i3 * 16 + c];
            a0.x += (lo2f(u0.x) + lo2f(u1.x)) + (lo2f(u2.x) + lo2f(u3.x));
            a0.y += (hi2f(u0.x) + hi2f(u1.x)) + (hi2f(u2.x) + hi2f(u3.x));
            a0.z += (lo2f(u0.y) + lo2f(u1.y)) + (lo2f(u2.y) + lo2f(u3.y));
            a0.w += (hi2f(u0.y) + hi2f(u1.y)) + (hi2f(u2.y) + hi2f(u3.y));
        }
        for (; e < hi; ++e) {
            uint2 u = yb[(size_t)scol[e - base] * 16 + c];
            a0.x += lo2f(u.x); a0.y += hi2f(u.x); a0.z += lo2f(u.y); a0.w += hi2f(u.y);
        }
        lo = beg1 > base ? beg1 : base;
        hi = end1 < base + cnt ? end1 : base + cnt;
        e = lo;
        for (; e + 4 <= hi; e += 4) {
            int i0 = scol[e - base], i1 = scol[e - base + 1];
            int i2 = scol[e - base + 2], i3 = scol[e - base + 3];
            uint2 u0 = yb[(size_t)i0 * 16 + c];
            uint2 u1 = yb[(size_t)i1 * 16 + c];
            uint2 u2 = yb[(size_t)i2 * 16 + c];
            uint2 u3 = yb[(size_t)i3 * 16 + c];
            a1.x += (lo2f(u0.x) + lo2f(u1.x)) + (lo2f(u2.x) + lo2f(u3.x));
            a1.y += (hi2f(u0.x) + hi2f(u1.x)) + (hi2f(u2.x) + hi2f(u3.x));
            a1.z += (lo2f(u0.y) + lo2f(u1.y)) + (lo2f(u2.y) + lo2f(u3.y));
            a1.w += (hi2f(u0.y) + hi2f(u1.y)) + (hi2f(u2.y) + hi2f(u3.y));
        }
        for (; e < hi; ++e) {
            uint2 u = yb[(size_t)scol[e - base] * 16 + c];
            a1.x += lo2f(u.x); a1.y += hi2f(u.x); a1.z += lo2f(u.y); a1.w += hi2f(u.y);
        }
    }
    a0.x = fmaxf(a0.x, 0.f); a0.y = fmaxf(a0.y, 0.f);
    a0.z = fmaxf(a0.z, 0.f); a0.w = fmaxf(a0.w, 0.f);
    a1.x = fmaxf(a1.x, 0.f); a1.y = fmaxf(a1.y, 0.f);
    a1.z = fmaxf(a1.z, 0.f); a1.w = fmaxf(a1.w, 0.f);
    sH[na0][c] = a0;
    sH[na0 + 16][c] = a1;
    __syncthreads();
    // ---- Phase B: 1 node x 4 outputs per thread ----
    int jl = t & 7, mg = t >> 3;
    int node = blk0 + mg;
    float4 ay = {0.f, 0.f, 0.f, 0.f};
    float4 az = bias[jl];
#pragma unroll 4
    for (int kc = 0; kc < 16; ++kc) {
        float4 h4 = sH[mg][kc];
#pragma unroll
        for (int tt = 0; tt < 4; ++tt) {
            float hv = fcomp(h4, tt);
            float4 wr = sR[(kc * 4 + tt) * 8 + jl];
            float4 wt = sT[(kc * 4 + tt) * 8 + jl];
            ay.x += hv * wr.x; ay.y += hv * wr.y;
            ay.z += hv * wr.z; ay.w += hv * wr.w;
            az.x += hv * wt.x; az.y += hv * wt.y;
            az.z += hv * wt.z; az.w += hv * wt.w;
        }
    }
    y3b[(size_t)node * 8 + jl] = pack4bf(ay);
    z3[(size_t)node * 8 + jl] = az;
}

// ====== fused L4: gather y3(bf16) + relu(z3+agg) + folded dot -> y4, z4 ======
// grid = NN/32 = 1250; LDS ~8 KB -> 8 blocks/CU
__global__ __launch_bounds__(256, 8) void fconv4_kernel(
        const uint2* __restrict__ yb,      // y3: N x 8 (bf16x4)
        const float4* __restrict__ z,      // z3: N x 8
        const int* __restrict__ rowptr,
        const int* __restrict__ col,
        const float* __restrict__ wf,      // 65
        float* __restrict__ y4,
        float* __restrict__ z4) {
    __shared__ float4 sH[32][9];
    __shared__ float4 sF[8], sRF[8];
    __shared__ float sB;
    __shared__ int scol[CCAP];
    int t = threadIdx.x;
    if (t < 8) sF[t] = ((const float4*)wf)[t];
    else if (t < 16) sRF[t - 8] = ((const float4*)wf)[t];
    else if (t == 16) sB = wf[64];
    int blk0 = blockIdx.x * 32;
    int ebeg = rowptr[blk0], eend = rowptr[blk0 + 32];
    int na = t >> 3, c = t & 7;
    int node = blk0 + na;
    int beg = rowptr[node], end = rowptr[node + 1];
    float4 a = z[(size_t)node * 8 + c];
    for (int base = ebeg; base < eend; base += CCAP) {
        int cnt = eend - base < CCAP ? eend - base : CCAP;
        __syncthreads();
        for (int i = t; i < cnt; i += 256) scol[i] = col[base + i];
        __syncthreads();
        int lo = beg > base ? beg : base;
        int hi = end < base + cnt ? end : base + cnt;
        int e = lo;
        for (; e + 4 <= hi; e += 4) {
            int i0 = scol[e - base], i1 = scol[e - base + 1];
            int i2 = scol[e - base + 2], i3 = scol[e - base + 3];
            uint2 u0 = yb[(size_t)i0 * 8 + c];
            uint2 u1 = yb[(size_t)i1 * 8 + c];
            uint2 u2 = yb[(size_t)i2 * 8 + c];
            uint2 u3 = yb[(size_t)i3 * 8 + c];
            a.x += (lo2f(u0.x) + lo2f(u1.x)) + (lo2f(u2.x) + lo2f(u3.x));
            a.y += (hi2f(u0.x) + hi2f(u1.x)) + (hi2f(u2.x) + hi2f(u3.x));
            a.z += (lo2f(u0.y) + lo2f(u1.y)) + (lo2f(u2.y) + lo2f(u3.y));
            a.w += (hi2f(u0.y) + hi2f(u1.y)) + (hi2f(u2.y) + hi2f(u3.y));
        }
        for (; e < hi; ++e) {
            uint2 u = yb[(size_t)scol[e - base] * 8 + c];
            a.x += lo2f(u.x); a.y += hi2f(u.x); a.z += lo2f(u.y); a.w += hi2f(u.y);
        }
    }
    a.x = fmaxf(a.x, 0.f); a.y = fmaxf(a.y, 0.f);
    a.z = fmaxf(a.z, 0.f); a.w = fmaxf(a.w, 0.f);
    sH[na][c] = a;
    __syncthreads();
    if (t < 32) {
        int nd = blk0 + t;
        float ay = 0.f, az = 0.f;
#pragma unroll
        for (int kc = 0; kc < 8; ++kc) {
            float4 h4 = sH[t][kc];
            float4 f = sF[kc], r = sRF[kc];
            ay += h4.x * f.x + h4.y * f.y + h4.z * f.z + h4.w * f.w;
            az += h4.x * r.x + h4.y * r.y + h4.z * r.z + h4.w * r.w;
        }
        y4[nd] = ay;
        z4[nd] = az + sB;
    }
}

// ====== gather + pool + last-block finalize ======
__global__ __launch_bounds__(256) void gpool_final_kernel(
        const float* __restrict__ y4,
        const float* __restrict__ z4,
        const int* __restrict__ rowptr,
        const int* __restrict__ col,
        const int* __restrict__ batch,
        float* __restrict__ sums,
        float* __restrict__ counts,
        int* __restrict__ ctr,
        const float* __restrict__ bfc,
        float* __restrict__ out) {
    __shared__ float ls[NG];
    __shared__ float lc[NG];
    __shared__ int sDone;
    if (threadIdx.x < NG) { ls[threadIdx.x] = 0.f; lc[threadIdx.x] = 0.f; }
    if (threadIdx.x == 0) sDone = 0;
    __syncthreads();
    int nd = blockIdx.x * 256 + threadIdx.x;
    if (nd < NN) {
        float v = z4[nd];
        int beg = rowptr[nd], end = rowptr[nd + 1];
        int e = beg;
        for (; e + 4 <= end; e += 4) {
            v += (y4[col[e]] + y4[col[e + 1]]) + (y4[col[e + 2]] + y4[col[e + 3]]);
        }
        for (; e < end; ++e) v += y4[col[e]];
        int g = batch[nd];
        atomicAdd(&ls[g], v);
        atomicAdd(&lc[g], 1.f);
    }
    __syncthreads();
    if (threadIdx.x < NG && lc[threadIdx.x] > 0.f) {
        atomicAdd(&sums[threadIdx.x], ls[threadIdx.x]);
        atomicAdd(&counts[threadIdx.x], lc[threadIdx.x]);
    }
    __threadfence();
    __syncthreads();
    if (threadIdx.x == 0) {
        if (atomicAdd(ctr, 1) == (int)gridDim.x - 1) sDone = 1;
    }
    __syncthreads();
    if (sDone && threadIdx.x < NG) {
        float s = atomicAdd(&sums[threadIdx.x], 0.f);   // coherent read
        float c = atomicAdd(&counts[threadIdx.x], 0.f);
        c = fmaxf(c, 1.0f);
        out[threadIdx.x] = s / c + bfc[0];
    }
}

extern "C" void kernel_launch(void* const* d_in, const int* in_sizes, int n_in,
                              void* d_out, int out_size, void* d_ws, size_t ws_size,
                              hipStream_t stream) {
    const float* x       = (const float*)d_in[0];
    const int*   ei      = (const int*)d_in[1];
    const int*   batch   = (const int*)d_in[2];
    const float* W1_rel  = (const float*)d_in[3];
    const float* b1      = (const float*)d_in[4];
    const float* W1_root = (const float*)d_in[5];
    const float* W2_rel  = (const float*)d_in[6];
    const float* b2      = (const float*)d_in[7];
    const float* W2_root = (const float*)d_in[8];
    const float* W3_rel  = (const float*)d_in[9];
    const float* b3      = (const float*)d_in[10];
    const float* W3_root = (const float*)d_in[11];
    const float* W4_rel  = (const float*)d_in[12];
    const float* b4      = (const float*)d_in[13];
    const float* W4_root = (const float*)d_in[14];
    const float* Wfc     = (const float*)d_in[15];
    const float* bfc     = (const float*)d_in[16];
    float* out = (float*)d_out;

    const int* src = ei;        // edge_index[0]
    const int* dst = ei + NE;   // edge_index[1]

    // workspace layout
    float* bufH   = (float*)d_ws;                    // N x 128  (h1, fp32)
    float* bufZ   = bufH + (size_t)NN * 128;         // N x 64   (z2, fp32)
    float* z3     = bufZ + (size_t)NN * 64;          // N x 32   (fp32)
    float* y4     = z3 + (size_t)NN * 32;            // N
    float* z4     = y4 + NN;                         // N
    float* wf     = z4 + NN;                         // 65 (pad 68)
    int*   deg    = (int*)(wf + 68);                 // N       -- zero block start
    float* sums   = (float*)(deg + NN);              // G
    float* counts = sums + NG;                       // G
    int*   ctr    = (int*)(counts + NG);             // 1       -- zero block end
    int*   rowptr = ctr + 1;                         // N+1
    int*   col    = rowptr + NN + 1;                 // E
    int*   bsum   = col + NE;                        // SCAN_NB (pad to even)
    int*   epos   = bsum + SCAN_NB + 1;              // E
    uint2* xb     = (uint2*)(epos + NE);             // N x 8  (bf16 x)
    uint2* y2b    = xb + (size_t)NN * 8;             // N x 16 (bf16 y2)
    uint2* y3b    = y2b + (size_t)NN * 16;           // N x 8  (bf16 y3)

    const int NZ = NN + 2 * NG + 1;   // deg + sums + counts + ctr

    // ---- prep: zero scratch, convert x->bf16, fold Wfc through L4 ----
    prep_kernel<<<NN * 8 / 256, 256, 0, stream>>>(
        deg, NZ, (const float4*)x, xb, W4_rel, W4_root, b4, Wfc, wf);

    // ---- build CSR (dst-sorted reverse adjacency) ----
    hist_kernel<<<(NE + 255) / 256, 256, 0, stream>>>(dst, deg, epos);
    scan1_kernel<<<SCAN_NB, 256, 0, stream>>>(deg, rowptr, bsum);
    scan23_kernel<<<SCAN_NB, 256, 0, stream>>>(rowptr, bsum);
    fill_kernel<<<(NE + 255) / 256, 256, 0, stream>>>(src, dst, rowptr, epos, col);

    // ---- Layer 1 fused: gather(xb) + conv 32->128 ----
    fconv1_kernel<<<NN / 32, 256, 0, stream>>>(
        xb, (const float4*)x, rowptr, col,
        (const float4*)W1_rel, (const float4*)W1_root, (const float4*)b1,
        (float4*)bufH);

    // ---- Layer 2 transform: h1 -> y2(bf16), z2(fp32) ----
    mmyz_kernel<<<NN / 32, 256, 0, stream>>>(
        (const float4*)bufH, (const float4*)W2_rel, (const float4*)W2_root,
        (const float4*)b2, y2b, (float4*)bufZ);

    // ---- Layer 3 fused: gather(y2b)+relu(z2+agg) + transform 64->32 ----
    fconv3_kernel<<<NN / 32, 256, 0, stream>>>(
        y2b, (const float4*)bufZ, rowptr, col,
        (const float4*)W3_rel, (const float4*)W3_root, (const float4*)b3,
        y3b, (float4*)z3);

    // ---- Layer 4 fused: gather(y3b)+relu(z3+agg) + folded dot -> y4, z4 ----
    fconv4_kernel<<<NN / 32, 256, 0, stream>>>(
        y3b, (const float4*)z3, rowptr, col, wf, y4, z4);

    // ---- final gather + pool + FC (last block finalizes) ----
    gpool_final_kernel<<<(NN + 255) / 256, 256, 0, stream>>>(
        y4, z4, rowptr, col, batch, sums, counts, ctr, bfc, out);
}

// Round 15
// 154.787 us; speedup vs baseline: 1.3645x; 1.0042x over previous
//
#include <hip/hip_runtime.h>

#define NN 40000
#define NE 640000
#define NG 64
#define SCAN_NB ((NN + 255) / 256)   // 157 blocks
#define CCAP 768                     // LDS col-staging chunk (ints)

__device__ __forceinline__ float fcomp(const float4& v, int t) {
    return t == 0 ? v.x : t == 1 ? v.y : t == 2 ? v.z : v.w;
}
// ---- bf16 pack/unpack (RNE) ----
__device__ __forceinline__ unsigned int pack2bf(float a, float b) {
    unsigned int ua = __float_as_uint(a);
    unsigned int ub = __float_as_uint(b);
    ua = (ua + 0x7fffu + ((ua >> 16) & 1u)) >> 16;
    ub = (ub + 0x7fffu + ((ub >> 16) & 1u)) >> 16;
    return ua | (ub << 16);
}
__device__ __forceinline__ uint2 pack4bf(const float4& v) {
    return make_uint2(pack2bf(v.x, v.y), pack2bf(v.z, v.w));
}
__device__ __forceinline__ float lo2f(unsigned int u) { return __uint_as_float(u << 16); }
__device__ __forceinline__ float hi2f(unsigned int u) { return __uint_as_float(u & 0xffff0000u); }
// accumulate 8 bf16 (one uint4) into two float4s
__device__ __forceinline__ void acc8(const uint4& u, float4& lo, float4& hi) {
    lo.x += lo2f(u.x); lo.y += hi2f(u.x); lo.z += lo2f(u.y); lo.w += hi2f(u.y);
    hi.x += lo2f(u.z); hi.y += hi2f(u.z); hi.z += lo2f(u.w); hi.w += hi2f(u.w);
}

// ===== prep: zero deg+sums+counts+ctr, convert x -> bf16, fold Wfc into L4 =====
__global__ __launch_bounds__(256) void prep_kernel(
        int* __restrict__ zp, int nz,
        const float4* __restrict__ x4,     // NN*8 float4
        uint2* __restrict__ xb,            // NN*8 uint2
        const float* __restrict__ W4rel,
        const float* __restrict__ W4root,
        const float* __restrict__ b4,
        const float* __restrict__ Wfc,
        float* __restrict__ wf) {
    int i = blockIdx.x * 256 + threadIdx.x;
    if (i < nz) zp[i] = 0;
    if (i < NN * 8) { float4 v = x4[i]; xb[i] = pack4bf(v); }
    if (blockIdx.x == 0) {
        int t = threadIdx.x;
        if (t < 32) {
            float a = 0.f, b = 0.f;
#pragma unroll
            for (int j = 0; j < 16; ++j) {
                float w = Wfc[j];
                a += W4rel[t * 16 + j] * w;
                b += W4root[t * 16 + j] * w;
            }
            wf[t] = a;
            wf[32 + t] = b;
        } else if (t == 32) {
            float s = 0.f;
#pragma unroll
            for (int j = 0; j < 16; ++j) s += b4[j] * Wfc[j];
            wf[64] = s;
        }
    }
}

// ================= CSR build =================
__global__ void hist_kernel(const int* __restrict__ dst, int* __restrict__ deg,
                            int* __restrict__ epos) {
    int e = blockIdx.x * blockDim.x + threadIdx.x;
    if (e < NE) epos[e] = atomicAdd(&deg[dst[e]], 1);
}

__global__ __launch_bounds__(256) void scan1_kernel(const int* __restrict__ deg,
                                                    int* __restrict__ rowptr,
                                                    int* __restrict__ bsum) {
    __shared__ int ws[4];
    __shared__ int wpre[4];
    int i = blockIdx.x * 256 + threadIdx.x;
    int lane = threadIdx.x & 63, wid = threadIdx.x >> 6;
    int v = (i < NN) ? deg[i] : 0;
    int incl = v;
#pragma unroll
    for (int off = 1; off < 64; off <<= 1) {
        int u = __shfl_up(incl, off, 64);
        if (lane >= off) incl += u;
    }
    if (lane == 63) ws[wid] = incl;
    __syncthreads();
    if (threadIdx.x == 0) {
        int s = 0;
#pragma unroll
        for (int w = 0; w < 4; ++w) { wpre[w] = s; s += ws[w]; }
        bsum[blockIdx.x] = s;
    }
    __syncthreads();
    if (i < NN) rowptr[i] = wpre[wid] + (incl - v);
}

// merged scan2+scan3
__global__ __launch_bounds__(256) void scan23_kernel(int* __restrict__ rowptr,
                                                     const int* __restrict__ bsum) {
    __shared__ int ws[4];
    int t = threadIdx.x, b = blockIdx.x;
    int v = (t < b) ? bsum[t] : 0;
#pragma unroll
    for (int off = 32; off; off >>= 1) v += __shfl_xor(v, off, 64);
    if ((t & 63) == 0) ws[t >> 6] = v;
    __syncthreads();
    int soff = ws[0] + ws[1] + ws[2] + ws[3];
    int i = b * 256 + t;
    if (i < NN) rowptr[i] += soff;
    if (b == SCAN_NB - 1 && t == 0) rowptr[NN] = soff + bsum[b];
}

__global__ void fill_kernel(const int* __restrict__ src, const int* __restrict__ dst,
                            const int* __restrict__ rowptr, const int* __restrict__ epos,
                            int* __restrict__ col) {
    int e = blockIdx.x * blockDim.x + threadIdx.x;
    if (e < NE) col[rowptr[dst[e]] + epos[e]] = src[e];
}

// ====== fused L1: gather xb (uint4-wide bf16) + conv 32->128 ======
// grid = NN/32 = 1250; 128 gather tasks (32 nodes x 4 uint4-slots)
__global__ __launch_bounds__(256, 4) void fconv1_kernel(
        const uint4* __restrict__ xb4,     // N x 4 (bf16x8)
        const float4* __restrict__ x,      // N x 8 (fp32, root term)
        const int* __restrict__ rowptr,
        const int* __restrict__ col,
        const float4* __restrict__ Wrel,   // 32 x 32
        const float4* __restrict__ Wroot,  // 32 x 32
        const float4* __restrict__ bias,   // 32
        float4* __restrict__ out) {        // N x 32
    __shared__ float4 sA[32][9];
    __shared__ float4 sR[32 * 32];
    __shared__ float4 sT[32 * 32];
    __shared__ int scol[CCAP];
    int t = threadIdx.x;
    for (int i = t; i < 32 * 32; i += 256) { sR[i] = Wrel[i]; sT[i] = Wroot[i]; }
    int blk0 = blockIdx.x * 32;
    int ebeg = rowptr[blk0], eend = rowptr[blk0 + 32];
    bool gat = t < 128;
    int na = t >> 2, c = t & 3;
    int node = blk0 + (gat ? na : 0);
    int beg = gat ? rowptr[node] : 0;
    int end = gat ? rowptr[node + 1] : 0;
    float4 aLo = {0.f, 0.f, 0.f, 0.f}, aHi = {0.f, 0.f, 0.f, 0.f};
    for (int base = ebeg; base < eend; base += CCAP) {
        int cnt = eend - base < CCAP ? eend - base : CCAP;
        __syncthreads();
        for (int i = t; i < cnt; i += 256) scol[i] = col[base + i];
        __syncthreads();
        if (gat) {
            int lo = beg > base ? beg : base;
            int hi = end < base + cnt ? end : base + cnt;
            int e = lo;
            for (; e + 4 <= hi; e += 4) {
                uint4 u0 = xb4[(size_t)scol[e - base] * 4 + c];
                uint4 u1 = xb4[(size_t)scol[e - base + 1] * 4 + c];
                uint4 u2 = xb4[(size_t)scol[e - base + 2] * 4 + c];
                uint4 u3 = xb4[(size_t)scol[e - base + 3] * 4 + c];
                acc8(u0, aLo, aHi); acc8(u1, aLo, aHi);
                acc8(u2, aLo, aHi); acc8(u3, aLo, aHi);
            }
            for (; e < hi; ++e) {
                uint4 u = xb4[(size_t)scol[e - base] * 4 + c];
                acc8(u, aLo, aHi);
            }
        }
    }
    if (gat) { sA[na][2 * c] = aLo; sA[na][2 * c + 1] = aHi; }
    __syncthreads();
    // ---- Phase B: 2 nodes x 8 outputs per thread (root term in fp32) ----
    int jg = t % 16, mg = t / 16;
    int n0 = blk0 + mg * 2;
    float4 bb0 = bias[2 * jg], bb1 = bias[2 * jg + 1];
    float4 acc00 = bb0, acc01 = bb1, acc10 = bb0, acc11 = bb1;
#pragma unroll 2
    for (int kc = 0; kc < 8; ++kc) {
        float4 a0 = sA[2 * mg][kc];
        float4 a1 = sA[2 * mg + 1][kc];
        float4 x0 = x[(size_t)n0 * 8 + kc];
        float4 x1 = x[(size_t)(n0 + 1) * 8 + kc];
#pragma unroll
        for (int tt = 0; tt < 4; ++tt) {
            int k = kc * 4 + tt;
            float4 wr0 = sR[k * 32 + 2 * jg], wr1 = sR[k * 32 + 2 * jg + 1];
            float4 wt0 = sT[k * 32 + 2 * jg], wt1 = sT[k * 32 + 2 * jg + 1];
            float av0 = fcomp(a0, tt), xv0 = fcomp(x0, tt);
            float av1 = fcomp(a1, tt), xv1 = fcomp(x1, tt);
            acc00.x += av0 * wr0.x + xv0 * wt0.x;
            acc00.y += av0 * wr0.y + xv0 * wt0.y;
            acc00.z += av0 * wr0.z + xv0 * wt0.z;
            acc00.w += av0 * wr0.w + xv0 * wt0.w;
            acc01.x += av0 * wr1.x + xv0 * wt1.x;
            acc01.y += av0 * wr1.y + xv0 * wt1.y;
            acc01.z += av0 * wr1.z + xv0 * wt1.z;
            acc01.w += av0 * wr1.w + xv0 * wt1.w;
            acc10.x += av1 * wr0.x + xv1 * wt0.x;
            acc10.y += av1 * wr0.y + xv1 * wt0.y;
            acc10.z += av1 * wr0.z + xv1 * wt0.z;
            acc10.w += av1 * wr0.w + xv1 * wt0.w;
            acc11.x += av1 * wr1.x + xv1 * wt1.x;
            acc11.y += av1 * wr1.y + xv1 * wt1.y;
            acc11.z += av1 * wr1.z + xv1 * wt1.z;
            acc11.w += av1 * wr1.w + xv1 * wt1.w;
        }
    }
    float4 r;
    r.x = fmaxf(acc00.x, 0.f); r.y = fmaxf(acc00.y, 0.f);
    r.z = fmaxf(acc00.z, 0.f); r.w = fmaxf(acc00.w, 0.f);
    out[(size_t)n0 * 32 + 2 * jg] = r;
    r.x = fmaxf(acc01.x, 0.f); r.y = fmaxf(acc01.y, 0.f);
    r.z = fmaxf(acc01.z, 0.f); r.w = fmaxf(acc01.w, 0.f);
    out[(size_t)n0 * 32 + 2 * jg + 1] = r;
    r.x = fmaxf(acc10.x, 0.f); r.y = fmaxf(acc10.y, 0.f);
    r.z = fmaxf(acc10.z, 0.f); r.w = fmaxf(acc10.w, 0.f);
    out[(size_t)(n0 + 1) * 32 + 2 * jg] = r;
    r.x = fmaxf(acc11.x, 0.f); r.y = fmaxf(acc11.y, 0.f);
    r.z = fmaxf(acc11.z, 0.f); r.w = fmaxf(acc11.w, 0.f);
    out[(size_t)(n0 + 1) * 32 + 2 * jg + 1] = r;
}

// ====== L2 transform: y2(bf16) = h1@W2rel, z2(fp32) = h1@W2root + b2 ======
__global__ __launch_bounds__(256, 6) void mmyz_kernel(
        const float4* __restrict__ h,      // N x 32
        const float4* __restrict__ Wrel,   // 128 x 16
        const float4* __restrict__ Wroot,  // 128 x 16
        const float4* __restrict__ bias,   // 16
        uint2* __restrict__ y2b,           // N x 16 (bf16x4)
        float4* __restrict__ z2) {
    __shared__ float4 sR[32 * 16];
    __shared__ float4 sT[32 * 16];
    int jl = threadIdx.x % 16;
    int mg = threadIdx.x / 16;
    int n0 = blockIdx.x * 32 + mg * 2;
    float4 bb = bias[jl];
    float4 ay0 = {0.f, 0.f, 0.f, 0.f}, ay1 = {0.f, 0.f, 0.f, 0.f};
    float4 az0 = bb, az1 = bb;
    for (int s = 0; s < 4; ++s) {
        if (s) __syncthreads();
        for (int i = threadIdx.x; i < 512; i += 256) {
            sR[i] = Wrel[s * 512 + i];
            sT[i] = Wroot[s * 512 + i];
        }
        __syncthreads();
#pragma unroll 2
        for (int kc = 0; kc < 8; ++kc) {
            float4 h0 = h[(size_t)n0 * 32 + s * 8 + kc];
            float4 h1 = h[(size_t)(n0 + 1) * 32 + s * 8 + kc];
#pragma unroll
            for (int tt = 0; tt < 4; ++tt) {
                float4 wr = sR[(kc * 4 + tt) * 16 + jl];
                float4 wt = sT[(kc * 4 + tt) * 16 + jl];
                float v0 = fcomp(h0, tt), v1 = fcomp(h1, tt);
                ay0.x += v0 * wr.x; ay0.y += v0 * wr.y;
                ay0.z += v0 * wr.z; ay0.w += v0 * wr.w;
                az0.x += v0 * wt.x; az0.y += v0 * wt.y;
                az0.z += v0 * wt.z; az0.w += v0 * wt.w;
                ay1.x += v1 * wr.x; ay1.y += v1 * wr.y;
                ay1.z += v1 * wr.z; ay1.w += v1 * wr.w;
                az1.x += v1 * wt.x; az1.y += v1 * wt.y;
                az1.z += v1 * wt.z; az1.w += v1 * wt.w;
            }
        }
    }
    y2b[(size_t)n0 * 16 + jl] = pack4bf(ay0);
    z2[(size_t)n0 * 16 + jl] = az0;
    y2b[(size_t)(n0 + 1) * 16 + jl] = pack4bf(ay1);
    z2[(size_t)(n0 + 1) * 16 + jl] = az1;
}

// ====== fused L3: gather y2 (uint4-wide bf16) + relu(z2+agg) + transform 64->32 ======
// grid = NN/32 = 1250; 256 gather tasks (32 nodes x 8 uint4-slots)
__global__ __launch_bounds__(256, 5) void fconv3_kernel(
        const uint4* __restrict__ yb4,     // y2: N x 8 (bf16x8)
        const float4* __restrict__ z,      // z2: N x 16
        const int* __restrict__ rowptr,
        const int* __restrict__ col,
        const float4* __restrict__ Wrel,   // 64 x 8
        const float4* __restrict__ Wroot,  // 64 x 8
        const float4* __restrict__ bias,   // 8
        uint2* __restrict__ y3b,           // N x 8 (bf16x4)
        float4* __restrict__ z3) {
    __shared__ float4 sH[32][17];
    __shared__ float4 sR[64 * 8];
    __shared__ float4 sT[64 * 8];
    __shared__ int scol[CCAP];
    int t = threadIdx.x;
    for (int i = t; i < 64 * 8; i += 256) { sR[i] = Wrel[i]; sT[i] = Wroot[i]; }
    int blk0 = blockIdx.x * 32;
    int ebeg = rowptr[blk0], eend = rowptr[blk0 + 32];
    int na = t >> 3, c = t & 7;
    int node = blk0 + na;
    int beg = rowptr[node], end = rowptr[node + 1];
    float4 aLo = z[(size_t)node * 16 + 2 * c];
    float4 aHi = z[(size_t)node * 16 + 2 * c + 1];
    for (int base = ebeg; base < eend; base += CCAP) {
        int cnt = eend - base < CCAP ? eend - base : CCAP;
        __syncthreads();
        for (int i = t; i < cnt; i += 256) scol[i] = col[base + i];
        __syncthreads();
        int lo = beg > base ? beg : base;
        int hi = end < base + cnt ? end : base + cnt;
        int e = lo;
        for (; e + 4 <= hi; e += 4) {
            uint4 u0 = yb4[(size_t)scol[e - base] * 8 + c];
            uint4 u1 = yb4[(size_t)scol[e - base + 1] * 8 + c];
            uint4 u2 = yb4[(size_t)scol[e - base + 2] * 8 + c];
            uint4 u3 = yb4[(size_t)scol[e - base + 3] * 8 + c];
            acc8(u0, aLo, aHi); acc8(u1, aLo, aHi);
            acc8(u2, aLo, aHi); acc8(u3, aLo, aHi);
        }
        for (; e < hi; ++e) {
            uint4 u = yb4[(size_t)scol[e - base] * 8 + c];
            acc8(u, aLo, aHi);
        }
    }
    aLo.x = fmaxf(aLo.x, 0.f); aLo.y = fmaxf(aLo.y, 0.f);
    aLo.z = fmaxf(aLo.z, 0.f); aLo.w = fmaxf(aLo.w, 0.f);
    aHi.x = fmaxf(aHi.x, 0.f); aHi.y = fmaxf(aHi.y, 0.f);
    aHi.z = fmaxf(aHi.z, 0.f); aHi.w = fmaxf(aHi.w, 0.f);
    sH[na][2 * c] = aLo;
    sH[na][2 * c + 1] = aHi;
    __syncthreads();
    // ---- Phase B: 1 node x 4 outputs per thread ----
    int jl = t & 7, mg = t >> 3;
    int nodeB = blk0 + mg;
    float4 ay = {0.f, 0.f, 0.f, 0.f};
    float4 az = bias[jl];
#pragma unroll 4
    for (int kc = 0; kc < 16; ++kc) {
        float4 h4 = sH[mg][kc];
#pragma unroll
        for (int tt = 0; tt < 4; ++tt) {
            float hv = fcomp(h4, tt);
            float4 wr = sR[(kc * 4 + tt) * 8 + jl];
            float4 wt = sT[(kc * 4 + tt) * 8 + jl];
            ay.x += hv * wr.x; ay.y += hv * wr.y;
            ay.z += hv * wr.z; ay.w += hv * wr.w;
            az.x += hv * wt.x; az.y += hv * wt.y;
            az.z += hv * wt.z; az.w += hv * wt.w;
        }
    }
    y3b[(size_t)nodeB * 8 + jl] = pack4bf(ay);
    z3[(size_t)nodeB * 8 + jl] = az;
}

// ====== fused L4: gather y3 (uint4-wide bf16) + relu(z3+agg) + folded dot ======
// grid = NN/32 = 1250; 128 gather tasks (32 nodes x 4 uint4-slots)
__global__ __launch_bounds__(256, 8) void fconv4_kernel(
        const uint4* __restrict__ yb4,     // y3: N x 4 (bf16x8)
        const float4* __restrict__ z,      // z3: N x 8
        const int* __restrict__ rowptr,
        const int* __restrict__ col,
        const float* __restrict__ wf,      // 65
        float* __restrict__ y4,
        float* __restrict__ z4) {
    __shared__ float4 sH[32][9];
    __shared__ float4 sF[8], sRF[8];
    __shared__ float sB;
    __shared__ int scol[CCAP];
    int t = threadIdx.x;
    if (t < 8) sF[t] = ((const float4*)wf)[t];
    else if (t < 16) sRF[t - 8] = ((const float4*)wf)[t];
    else if (t == 16) sB = wf[64];
    int blk0 = blockIdx.x * 32;
    int ebeg = rowptr[blk0], eend = rowptr[blk0 + 32];
    bool gat = t < 128;
    int na = t >> 2, c = t & 3;
    int node = blk0 + (gat ? na : 0);
    int beg = gat ? rowptr[node] : 0;
    int end = gat ? rowptr[node + 1] : 0;
    float4 aLo = {0.f, 0.f, 0.f, 0.f}, aHi = {0.f, 0.f, 0.f, 0.f};
    if (gat) {
        aLo = z[(size_t)node * 8 + 2 * c];
        aHi = z[(size_t)node * 8 + 2 * c + 1];
    }
    for (int base = ebeg; base < eend; base += CCAP) {
        int cnt = eend - base < CCAP ? eend - base : CCAP;
        __syncthreads();
        for (int i = t; i < cnt; i += 256) scol[i] = col[base + i];
        __syncthreads();
        if (gat) {
            int lo = beg > base ? beg : base;
            int hi = end < base + cnt ? end : base + cnt;
            int e = lo;
            for (; e + 4 <= hi; e += 4) {
                uint4 u0 = yb4[(size_t)scol[e - base] * 4 + c];
                uint4 u1 = yb4[(size_t)scol[e - base + 1] * 4 + c];
                uint4 u2 = yb4[(size_t)scol[e - base + 2] * 4 + c];
                uint4 u3 = yb4[(size_t)scol[e - base + 3] * 4 + c];
                acc8(u0, aLo, aHi); acc8(u1, aLo, aHi);
                acc8(u2, aLo, aHi); acc8(u3, aLo, aHi);
            }
            for (; e < hi; ++e) {
                uint4 u = yb4[(size_t)scol[e - base] * 4 + c];
                acc8(u, aLo, aHi);
            }
        }
    }
    if (gat) {
        aLo.x = fmaxf(aLo.x, 0.f); aLo.y = fmaxf(aLo.y, 0.f);
        aLo.z = fmaxf(aLo.z, 0.f); aLo.w = fmaxf(aLo.w, 0.f);
        aHi.x = fmaxf(aHi.x, 0.f); aHi.y = fmaxf(aHi.y, 0.f);
        aHi.z = fmaxf(aHi.z, 0.f); aHi.w = fmaxf(aHi.w, 0.f);
        sH[na][2 * c] = aLo;
        sH[na][2 * c + 1] = aHi;
    }
    __syncthreads();
    if (t < 32) {
        int nd = blk0 + t;
        float ay = 0.f, az = 0.f;
#pragma unroll
        for (int kc = 0; kc < 8; ++kc) {
            float4 h4 = sH[t][kc];
            float4 f = sF[kc], r = sRF[kc];
            ay += h4.x * f.x + h4.y * f.y + h4.z * f.z + h4.w * f.w;
            az += h4.x * r.x + h4.y * r.y + h4.z * r.z + h4.w * r.w;
        }
        y4[nd] = ay;
        z4[nd] = az + sB;
    }
}

// ====== gather + pool + last-block finalize ======
__global__ __launch_bounds__(256) void gpool_final_kernel(
        const float* __restrict__ y4,
        const float* __restrict__ z4,
        const int* __restrict__ rowptr,
        const int* __restrict__ col,
        const int* __restrict__ batch,
        float* __restrict__ sums,
        float* __restrict__ counts,
        int* __restrict__ ctr,
        const float* __restrict__ bfc,
        float* __restrict__ out) {
    __shared__ float ls[NG];
    __shared__ float lc[NG];
    __shared__ int sDone;
    if (threadIdx.x < NG) { ls[threadIdx.x] = 0.f; lc[threadIdx.x] = 0.f; }
    if (threadIdx.x == 0) sDone = 0;
    __syncthreads();
    int nd = blockIdx.x * 256 + threadIdx.x;
    if (nd < NN) {
        float v = z4[nd];
        int beg = rowptr[nd], end = rowptr[nd + 1];
        int e = beg;
        for (; e + 4 <= end; e += 4) {
            v += (y4[col[e]] + y4[col[e + 1]]) + (y4[col[e + 2]] + y4[col[e + 3]]);
        }
        for (; e < end; ++e) v += y4[col[e]];
        int g = batch[nd];
        atomicAdd(&ls[g], v);
        atomicAdd(&lc[g], 1.f);
    }
    __syncthreads();
    if (threadIdx.x < NG && lc[threadIdx.x] > 0.f) {
        atomicAdd(&sums[threadIdx.x], ls[threadIdx.x]);
        atomicAdd(&counts[threadIdx.x], lc[threadIdx.x]);
    }
    __threadfence();
    __syncthreads();
    if (threadIdx.x == 0) {
        if (atomicAdd(ctr, 1) == (int)gridDim.x - 1) sDone = 1;
    }
    __syncthreads();
    if (sDone && threadIdx.x < NG) {
        float s = atomicAdd(&sums[threadIdx.x], 0.f);   // coherent read
        float c = atomicAdd(&counts[threadIdx.x], 0.f);
        c = fmaxf(c, 1.0f);
        out[threadIdx.x] = s / c + bfc[0];
    }
}

extern "C" void kernel_launch(void* const* d_in, const int* in_sizes, int n_in,
                              void* d_out, int out_size, void* d_ws, size_t ws_size,
                              hipStream_t stream) {
    const float* x       = (const float*)d_in[0];
    const int*   ei      = (const int*)d_in[1];
    const int*   batch   = (const int*)d_in[2];
    const float* W1_rel  = (const float*)d_in[3];
    const float* b1      = (const float*)d_in[4];
    const float* W1_root = (const float*)d_in[5];
    const float* W2_rel  = (const float*)d_in[6];
    const float* b2      = (const float*)d_in[7];
    const float* W2_root = (const float*)d_in[8];
    const float* W3_rel  = (const float*)d_in[9];
    const float* b3      = (const float*)d_in[10];
    const float* W3_root = (const float*)d_in[11];
    const float* W4_rel  = (const float*)d_in[12];
    const float* b4      = (const float*)d_in[13];
    const float* W4_root = (const float*)d_in[14];
    const float* Wfc     = (const float*)d_in[15];
    const float* bfc     = (const float*)d_in[16];
    float* out = (float*)d_out;

    const int* src = ei;        // edge_index[0]
    const int* dst = ei + NE;   // edge_index[1]

    // workspace layout (16B-aligned sections verified)
    float* bufH   = (float*)d_ws;                    // N x 128  (h1, fp32)
    float* bufZ   = bufH + (size_t)NN * 128;         // N x 64   (z2, fp32)
    float* z3     = bufZ + (size_t)NN * 64;          // N x 32   (fp32)
    float* y4     = z3 + (size_t)NN * 32;            // N
    float* z4     = y4 + NN;                         // N
    float* wf     = z4 + NN;                         // 65 (pad 68)
    int*   deg    = (int*)(wf + 68);                 // N       -- zero block start
    float* sums   = (float*)(deg + NN);              // G
    float* counts = sums + NG;                       // G
    int*   ctr    = (int*)(counts + NG);             // 1       -- zero block end
    int*   rowptr = ctr + 1;                         // N+1
    int*   col    = rowptr + NN + 1;                 // E
    int*   bsum   = col + NE;                        // SCAN_NB (pad)
    int*   epos   = bsum + SCAN_NB + 1;              // E
    uint2* xb     = (uint2*)(epos + NE);             // N x 8  (bf16 x)
    uint2* y2b    = xb + (size_t)NN * 8;             // N x 16 (bf16 y2)
    uint2* y3b    = y2b + (size_t)NN * 16;           // N x 8  (bf16 y3)

    const int NZ = NN + 2 * NG + 1;   // deg + sums + counts + ctr

    // ---- prep: zero scratch, convert x->bf16, fold Wfc through L4 ----
    prep_kernel<<<NN * 8 / 256, 256, 0, stream>>>(
        deg, NZ, (const float4*)x, xb, W4_rel, W4_root, b4, Wfc, wf);

    // ---- build CSR (dst-sorted reverse adjacency) ----
    hist_kernel<<<(NE + 255) / 256, 256, 0, stream>>>(dst, deg, epos);
    scan1_kernel<<<SCAN_NB, 256, 0, stream>>>(deg, rowptr, bsum);
    scan23_kernel<<<SCAN_NB, 256, 0, stream>>>(rowptr, bsum);
    fill_kernel<<<(NE + 255) / 256, 256, 0, stream>>>(src, dst, rowptr, epos, col);

    // ---- Layer 1 fused: gather(xb, 16B lanes) + conv 32->128 ----
    fconv1_kernel<<<NN / 32, 256, 0, stream>>>(
        (const uint4*)xb, (const float4*)x, rowptr, col,
        (const float4*)W1_rel, (const float4*)W1_root, (const float4*)b1,
        (float4*)bufH);

    // ---- Layer 2 transform: h1 -> y2(bf16), z2(fp32) ----
    mmyz_kernel<<<NN / 32, 256, 0, stream>>>(
        (const float4*)bufH, (const float4*)W2_rel, (const float4*)W2_root,
        (const float4*)b2, y2b, (float4*)bufZ);

    // ---- Layer 3 fused: gather(y2b, 16B lanes) + relu(z2+agg) + transform ----
    fconv3_kernel<<<NN / 32, 256, 0, stream>>>(
        (const uint4*)y2b, (const float4*)bufZ, rowptr, col,
        (const float4*)W3_rel, (const float4*)W3_root, (const float4*)b3,
        y3b, (float4*)z3);

    // ---- Layer 4 fused: gather(y3b, 16B lanes) + relu(z3+agg) + folded dot ----
    fconv4_kernel<<<NN / 32, 256, 0, stream>>>(
        (const uint4*)y3b, (const float4*)z3, rowptr, col, wf, y4, z4);

    // ---- final gather + pool + FC (last block finalizes) ----
    gpool_final_kernel<<<(NN + 255) / 256, 256, 0, stream>>>(
        y4, z4, rowptr, col, batch, sums, counts, ctr, bfc, out);
}